// Round 3
// baseline (1295.789 us; speedup 1.0000x reference)
//
#include <hip/hip_runtime.h>
#include <stdint.h>

// ---------- device globals: dtype flag + BN stats ----------
__device__ int   g_isf32;
__device__ float g_stats[512];  // [0:128) s1sum, [128:256) s1sq, [256:384) s2sum, [384:512) s2sq

// ---------- bf16 helpers ----------
__device__ __forceinline__ float bf2f(unsigned short u) {
  union { unsigned int i; float f; } v; v.i = ((unsigned int)u) << 16; return v.f;
}
__device__ __forceinline__ unsigned short f2bf(float f) {
  union { float f; unsigned int i; } v; v.f = f;
  unsigned int r = v.i + 0x7FFFu + ((v.i >> 16) & 1u);
  return (unsigned short)(r >> 16);
}
__device__ __forceinline__ unsigned int pk2(float a, float b) {
  return (unsigned int)f2bf(a) | ((unsigned int)f2bf(b) << 16);
}
// dtype-flex input load: f ? fp32 : bf16
__device__ __forceinline__ float ldi(const void* p, size_t i, int f) {
  return f ? ((const float*)p)[i] : bf2f(((const unsigned short*)p)[i]);
}

// ---------- K0: dtype detector + stats zeroing ----------
// Interpret first 4096 ushorts of x as bf16. True-bf16 N(0,1) data has sane
// exponents; fp32 data's low halves have uniform-random exponents (~20% insane).
__global__ void k_detect(const unsigned short* __restrict__ x) {
  __shared__ int cnt;
  const int t = threadIdx.x;
  if (t == 0) cnt = 0;
  g_stats[t] = 0.f; g_stats[t + 256] = 0.f;
  __syncthreads();
  int c = 0;
  for (int j = 0; j < 16; j++) {
    unsigned short u = x[t * 16 + j];
    int e = (u >> 7) & 0xFF;
    if (e == 0xFF || (e != 0 && e <= 100)) c++;
  }
  atomicAdd(&cnt, c);
  __syncthreads();
  if (t == 0) g_isf32 = (cnt > 256) ? 1 : 0;
}

// ---------- K_prep: weights -> fp32 GEMM-friendly layouts ----------
// wdcnT[k][c][o] (9*256*128) ; wctT[kr][kc][i][o] (4*4*128*128) ; woffT[ci][k][27]
__global__ void k_prep(const void* __restrict__ w_dcn, const void* __restrict__ w_ct,
                       const void* __restrict__ w_off,
                       float* __restrict__ wdcnT, float* __restrict__ wctT,
                       float* __restrict__ woffT) {
  const int f = g_isf32;
  int idx = blockIdx.x * 256 + threadIdx.x;
  if (idx < 294912) {
    int k = idx / 32768, c = (idx >> 7) & 255, o = idx & 127;
    wdcnT[idx] = ldi(w_dcn, (size_t)(o * 256 + c) * 9 + k, f);
  }
  int i2 = idx - 294912;
  if (i2 >= 0 && i2 < 262144) {
    int kr = i2 >> 16, kc = (i2 >> 14) & 3, i = (i2 >> 7) & 127, o = i2 & 127;
    wctT[i2] = ldi(w_ct, (size_t)((i * 128 + o) * 4 + kr) * 4 + kc, f);
  }
  int i3 = idx - (294912 + 262144);
  if (i3 >= 0 && i3 < 62208) {
    int ci = i3 / 243, r = i3 - ci * 243, k = r / 27, c = r - (r / 27) * 27;
    woffT[i3] = ldi(w_off, (size_t)(c * 256 + ci) * 9 + k, f);
  }
}

// ---------- K1: 3x3 offset conv, pad 1.  om (8,27,64,64) fp32 ----------
__global__ __launch_bounds__(256) void k_offconv(
    const void* __restrict__ x, const void* __restrict__ b_off,
    const float* __restrict__ woffT, float* __restrict__ om) {
  const int f = g_isf32;
  const int h = blockIdx.x, b = blockIdx.y;
  const int t = threadIdx.x;
  const int cg = t & 31, wg = t >> 5;
  const int w0 = wg * 8;
  __shared__ float xs[32 * 204];   // [ci][3][68], 26112 B
  float acc[8];
#pragma unroll
  for (int i = 0; i < 8; i++) acc[i] = 0.f;

  for (int cb = 0; cb < 256; cb += 32) {
    __syncthreads();
    for (int e = t; e < 32 * 192; e += 256) {
      int ci = e / 192, r = e - ci * 192;
      int dh = r >> 6, w = r & 63;
      int row = h + dh - 1;
      float v = 0.f;
      if (row >= 0 && row < 64)
        v = ldi(x, ((size_t)((b * 256 + cb + ci) * 64 + row) << 6) + w, f);
      xs[ci * 204 + dh * 68 + w + 1] = v;
    }
    for (int e = t; e < 96; e += 256) {
      int base = (e / 3) * 204 + (e - (e / 3) * 3) * 68;
      xs[base] = 0.f; xs[base + 65] = 0.f; xs[base + 66] = 0.f; xs[base + 67] = 0.f;
    }
    __syncthreads();

    for (int ci = 0; ci < 32; ci++) {
      float xr[3][12];
#pragma unroll
      for (int dh = 0; dh < 3; dh++) {
        const float* p = &xs[ci * 204 + dh * 68 + w0];
        float4 q0 = *(const float4*)(p);
        float4 q1 = *(const float4*)(p + 4);
        float4 q2 = *(const float4*)(p + 8);
        xr[dh][0] = q0.x; xr[dh][1] = q0.y; xr[dh][2] = q0.z; xr[dh][3] = q0.w;
        xr[dh][4] = q1.x; xr[dh][5] = q1.y; xr[dh][6] = q1.z; xr[dh][7] = q1.w;
        xr[dh][8] = q2.x; xr[dh][9] = q2.y; xr[dh][10] = q2.z; xr[dh][11] = q2.w;
      }
      if (cg < 27) {
        const float* wp = &woffT[(size_t)(cb + ci) * 243 + cg];
#pragma unroll
        for (int k = 0; k < 9; k++) {
          float wk = wp[k * 27];
          const int dh = k / 3, dx = k - (k / 3) * 3;
#pragma unroll
          for (int wi = 0; wi < 8; wi++)
            acc[wi] = fmaf(wk, xr[dh][wi + dx], acc[wi]);
        }
      }
    }
  }
  if (cg < 27) {
    float bo = ldi(b_off, cg, f);
    float* op = &om[(size_t)((b * 27 + cg) * 64 + h) * 64 + w0];
#pragma unroll
    for (int wi = 0; wi < 8; wi++) op[wi] = acc[wi] + bo;
  }
}

// ---------- K2: deformable sampling + DCN einsum + bias + stats ----------
// block = (h, b).  S chunks of 64 channels (16 KB LDS); 128x64 GEMM, 8x4 tile.
__global__ __launch_bounds__(256) void k_dcn(
    const void* __restrict__ x, const float* __restrict__ om,
    const float* __restrict__ wdcnT, const void* __restrict__ b_dcn,
    unsigned short* __restrict__ h1) {
  const int f = g_isf32;
  const int h = blockIdx.x, b = blockIdx.y;
  const int t = threadIdx.x;
  __shared__ float S[64 * 64];     // 16384 B
  __shared__ int   midx[64][4];
  __shared__ float mwgt[64][4];
  const int og = t >> 4, pg = t & 15;
  const int pA = t & 63, cgA = t >> 6;
  float acc[8][4];
#pragma unroll
  for (int j = 0; j < 8; j++)
#pragma unroll
    for (int i = 0; i < 4; i++) acc[j][i] = 0.f;

  for (int k = 0; k < 9; k++) {
    if (t < 64) {
      const int w = t;
      const float* ob = &om[(size_t)(b * 27) * 4096 + h * 64 + w];
      float oy = ob[(size_t)k * 4096];
      float ox = ob[(size_t)(k + 9) * 4096];
      float mm = ob[(size_t)(k + 18) * 4096];
      float msk = 1.f / (1.f + expf(-mm));
      float py = oy + (float)(h - 1 + k / 3);
      float px = ox + (float)(w - 1 + (k - (k / 3) * 3));
      float y0f = floorf(py), x0f = floorf(px);
      float ly = py - y0f, lx = px - x0f;
      int y0 = (int)y0f, x0 = (int)x0f;
      int y1 = y0 + 1, x1 = x0 + 1;
      float fy0 = (y0 >= 0 && y0 < 64) ? 1.f : 0.f;
      float fy1 = (y1 >= 0 && y1 < 64) ? 1.f : 0.f;
      float fx0 = (x0 >= 0 && x0 < 64) ? 1.f : 0.f;
      float fx1 = (x1 >= 0 && x1 < 64) ? 1.f : 0.f;
      int y0c = min(max(y0, 0), 63), y1c = min(max(y1, 0), 63);
      int x0c = min(max(x0, 0), 63), x1c = min(max(x1, 0), 63);
      midx[w][0] = y0c * 64 + x0c;
      midx[w][1] = y0c * 64 + x1c;
      midx[w][2] = y1c * 64 + x0c;
      midx[w][3] = y1c * 64 + x1c;
      mwgt[w][0] = (1.f - ly) * (1.f - lx) * msk * fy0 * fx0;
      mwgt[w][1] = (1.f - ly) * lx * msk * fy0 * fx1;
      mwgt[w][2] = ly * (1.f - lx) * msk * fy1 * fx0;
      mwgt[w][3] = ly * lx * msk * fy1 * fx1;
    }
    for (int ch = 0; ch < 4; ch++) {   // 4 chunks of 64 input channels
      __syncthreads();
      {
        const int i0 = midx[pA][0], i1 = midx[pA][1], i2 = midx[pA][2], i3 = midx[pA][3];
        const float g0 = mwgt[pA][0], g1 = mwgt[pA][1], g2 = mwgt[pA][2], g3 = mwgt[pA][3];
        const size_t cbase = (size_t)(b * 256 + ch * 64 + cgA * 16) * 4096;
        float* Sp = &S[(cgA * 16) * 64 + pA];
#pragma unroll 4
        for (int j = 0; j < 16; j++) {
          const size_t xo = cbase + (size_t)j * 4096;
          float v = g0 * ldi(x, xo + i0, f) + g1 * ldi(x, xo + i1, f)
                  + g2 * ldi(x, xo + i2, f) + g3 * ldi(x, xo + i3, f);
          Sp[j * 64] = v;
        }
      }
      __syncthreads();
      const float* wk = wdcnT + (size_t)k * 32768 + (size_t)(ch * 64) * 128;
#pragma unroll 2
      for (int c2 = 0; c2 < 64; c2++) {
        float4 a0 = *(const float4*)&wk[c2 * 128 + og * 8];
        float4 a1 = *(const float4*)&wk[c2 * 128 + og * 8 + 4];
        float4 s4 = *(const float4*)&S[c2 * 64 + pg * 4];
        float aa[8] = {a0.x, a0.y, a0.z, a0.w, a1.x, a1.y, a1.z, a1.w};
        float ss[4] = {s4.x, s4.y, s4.z, s4.w};
#pragma unroll
        for (int j = 0; j < 8; j++)
#pragma unroll
          for (int i = 0; i < 4; i++)
            acc[j][i] = fmaf(aa[j], ss[i], acc[j][i]);
      }
    }
  }
#pragma unroll
  for (int j = 0; j < 8; j++) {
    const int o = og * 8 + j;
    float bd = ldi(b_dcn, o, f);
    float v0 = acc[j][0] + bd, v1 = acc[j][1] + bd, v2 = acc[j][2] + bd, v3 = acc[j][3] + bd;
    float s = v0 + v1 + v2 + v3;
    float q = v0 * v0 + v1 * v1 + v2 * v2 + v3 * v3;
    uint2 pkv = make_uint2(pk2(v0, v1), pk2(v2, v3));
    *(uint2*)(h1 + (size_t)((b * 128 + o) * 64 + h) * 64 + pg * 4) = pkv;
#pragma unroll
    for (int m = 1; m < 16; m <<= 1) {
      s += __shfl_xor(s, m, 64);
      q += __shfl_xor(q, m, 64);
    }
    if (pg == 0) { atomicAdd(&g_stats[o], s); atomicAdd(&g_stats[128 + o], q); }
  }
}

// ---------- K3: BN1 + ReLU in place on h1 (bf16 internal) ----------
__global__ void k_bn1(unsigned short* __restrict__ h1, const void* __restrict__ g1,
                      const void* __restrict__ be1) {
  const int f = g_isf32;
  int gid = blockIdx.x * 256 + threadIdx.x;
  size_t base = (size_t)gid * 8;
  int o = (int)((base >> 12) & 127);
  float mu = g_stats[o] * (1.f / 32768.f);
  float var = g_stats[128 + o] * (1.f / 32768.f) - mu * mu;
  float sc = rsqrtf(var + 1e-5f) * ldi(g1, o, f);
  float sh = ldi(be1, o, f) - mu * sc;
  uint4 p = *(const uint4*)(h1 + base);
  unsigned int pp[4] = {p.x, p.y, p.z, p.w};
  unsigned int r[4];
#pragma unroll
  for (int i = 0; i < 4; i++) {
    float f0 = fmaxf(fmaf(bf2f((unsigned short)(pp[i] & 0xffff)), sc, sh), 0.f);
    float f1 = fmaxf(fmaf(bf2f((unsigned short)(pp[i] >> 16)), sc, sh), 0.f);
    r[i] = pk2(f0, f1);
  }
  *(uint4*)(h1 + base) = make_uint4(r[0], r[1], r[2], r[3]);
}

// ---------- K4: 4x4 stride-2 transposed conv (parity 2x2 taps) + stats ----------
__global__ __launch_bounds__(256) void k_ctconv(
    const unsigned short* __restrict__ h1n, const float* __restrict__ wctT,
    void* __restrict__ out2) {
  const int f = g_isf32;
  const int y = blockIdx.x, b = blockIdx.y;
  const int t = threadIdx.x;
  const int og = t >> 3, xg = t & 7;
  __shared__ float hs[2 * 32 * 68];   // 17408 B
  int kr0, kr1, r0, r1;
  if ((y & 1) == 0) { kr0 = 1; r0 = y >> 1; kr1 = 3; r1 = (y >> 1) - 1; }
  else              { kr0 = 0; r0 = (y + 1) >> 1; kr1 = 2; r1 = (y - 1) >> 1; }
  float acc[4][16];
#pragma unroll
  for (int j = 0; j < 4; j++)
#pragma unroll
    for (int i = 0; i < 16; i++) acc[j][i] = 0.f;

  for (int ihc = 0; ihc < 4; ihc++) {   // 4 chunks of 32 input channels
    __syncthreads();
    for (int e = t; e < 2 * 32 * 64; e += 256) {
      int rr = e >> 11, rem = e & 2047, il = rem >> 6, w = rem & 63;
      int i = ihc * 32 + il;
      int row = rr ? r1 : r0;
      float v = 0.f;
      if (row >= 0 && row < 64)
        v = bf2f(h1n[(size_t)((b * 128 + i) * 64 + row) * 64 + w]);
      hs[(rr * 32 + il) * 68 + w + 1] = v;
    }
    for (int e = t; e < 64; e += 256) {
      int base = e * 68;
      hs[base] = 0.f; hs[base + 65] = 0.f; hs[base + 66] = 0.f; hs[base + 67] = 0.f;
    }
    __syncthreads();
    for (int il = 0; il < 32; il++) {
      const int i = ihc * 32 + il;
      float br[2][12];
#pragma unroll
      for (int rr = 0; rr < 2; rr++) {
        const float* p = &hs[(rr * 32 + il) * 68 + xg * 8];
        float4 q0 = *(const float4*)(p);
        float4 q1 = *(const float4*)(p + 4);
        float4 q2 = *(const float4*)(p + 8);
        br[rr][0] = q0.x; br[rr][1] = q0.y; br[rr][2] = q0.z; br[rr][3] = q0.w;
        br[rr][4] = q1.x; br[rr][5] = q1.y; br[rr][6] = q1.z; br[rr][7] = q1.w;
        br[rr][8] = q2.x; br[rr][9] = q2.y; br[rr][10] = q2.z; br[rr][11] = q2.w;
      }
      float a[2][4][4];
#pragma unroll
      for (int rr = 0; rr < 2; rr++) {
        const int krr = rr ? kr1 : kr0;
#pragma unroll
        for (int kc = 0; kc < 4; kc++) {
          float4 av = *(const float4*)&wctT[((size_t)(krr * 4 + kc) * 128 + i) * 128 + og * 4];
          a[rr][kc][0] = av.x; a[rr][kc][1] = av.y; a[rr][kc][2] = av.z; a[rr][kc][3] = av.w;
        }
      }
#pragma unroll
      for (int xi = 0; xi < 16; xi++) {
        const int u = xi >> 1;
        const int kcA = (xi & 1) ? 0 : 1;
        const int lwA = (xi & 1) ? u + 2 : u + 1;
        const int kcB = (xi & 1) ? 2 : 3;
        const int lwB = (xi & 1) ? u + 1 : u;
#pragma unroll
        for (int rr = 0; rr < 2; rr++) {
#pragma unroll
          for (int j = 0; j < 4; j++) {
            acc[j][xi] = fmaf(a[rr][kcA][j], br[rr][lwA], acc[j][xi]);
            acc[j][xi] = fmaf(a[rr][kcB][j], br[rr][lwB], acc[j][xi]);
          }
        }
      }
    }
  }
#pragma unroll
  for (int j = 0; j < 4; j++) {
    const int o = og * 4 + j;
    float s = 0.f, q = 0.f;
#pragma unroll
    for (int xi = 0; xi < 16; xi++) { s += acc[j][xi]; q += acc[j][xi] * acc[j][xi]; }
    size_t ofs = (size_t)((b * 128 + o) * 128 + y) * 128 + xg * 16;
    if (f) {
      float* op = (float*)out2 + ofs;
#pragma unroll
      for (int v4 = 0; v4 < 4; v4++)
        ((float4*)op)[v4] = make_float4(acc[j][4 * v4], acc[j][4 * v4 + 1],
                                        acc[j][4 * v4 + 2], acc[j][4 * v4 + 3]);
    } else {
      unsigned int w_[8];
#pragma unroll
      for (int xi = 0; xi < 8; xi++) w_[xi] = pk2(acc[j][2 * xi], acc[j][2 * xi + 1]);
      unsigned short* op = (unsigned short*)out2 + ofs;
      *(uint4*)(op)     = make_uint4(w_[0], w_[1], w_[2], w_[3]);
      *(uint4*)(op + 8) = make_uint4(w_[4], w_[5], w_[6], w_[7]);
    }
#pragma unroll
    for (int m = 1; m < 8; m <<= 1) {
      s += __shfl_xor(s, m, 64);
      q += __shfl_xor(q, m, 64);
    }
    if (xg == 0) { atomicAdd(&g_stats[256 + o], s); atomicAdd(&g_stats[384 + o], q); }
  }
}

// ---------- K5: BN2 + ReLU in place on d_out ----------
__global__ void k_bn2(void* __restrict__ out2, const void* __restrict__ g2,
                      const void* __restrict__ be2) {
  const int f = g_isf32;
  int gid = blockIdx.x * 256 + threadIdx.x;
  size_t base = (size_t)gid * 8;
  int o = (int)((base >> 14) & 127);
  float mu = g_stats[256 + o] * (1.f / 131072.f);
  float var = g_stats[384 + o] * (1.f / 131072.f) - mu * mu;
  float sc = rsqrtf(var + 1e-5f) * ldi(g2, o, f);
  float sh = ldi(be2, o, f) - mu * sc;
  if (f) {
    float4* op = (float4*)out2 + gid * 2;
    float4 p0 = op[0], p1 = op[1];
    p0.x = fmaxf(fmaf(p0.x, sc, sh), 0.f); p0.y = fmaxf(fmaf(p0.y, sc, sh), 0.f);
    p0.z = fmaxf(fmaf(p0.z, sc, sh), 0.f); p0.w = fmaxf(fmaf(p0.w, sc, sh), 0.f);
    p1.x = fmaxf(fmaf(p1.x, sc, sh), 0.f); p1.y = fmaxf(fmaf(p1.y, sc, sh), 0.f);
    p1.z = fmaxf(fmaf(p1.z, sc, sh), 0.f); p1.w = fmaxf(fmaf(p1.w, sc, sh), 0.f);
    op[0] = p0; op[1] = p1;
  } else {
    unsigned short* ob = (unsigned short*)out2 + base;
    uint4 p = *(const uint4*)ob;
    unsigned int pp[4] = {p.x, p.y, p.z, p.w};
    unsigned int r[4];
#pragma unroll
    for (int i = 0; i < 4; i++) {
      float f0 = fmaxf(fmaf(bf2f((unsigned short)(pp[i] & 0xffff)), sc, sh), 0.f);
      float f1 = fmaxf(fmaf(bf2f((unsigned short)(pp[i] >> 16)), sc, sh), 0.f);
      r[i] = pk2(f0, f1);
    }
    *(uint4*)ob = make_uint4(r[0], r[1], r[2], r[3]);
  }
}

// ---------- launch ----------
extern "C" void kernel_launch(void* const* d_in, const int* in_sizes, int n_in,
                              void* d_out, int out_size, void* d_ws, size_t ws_size,
                              hipStream_t stream) {
  const void* x     = d_in[0];
  const void* w_off = d_in[1];
  const void* b_off = d_in[2];
  const void* w_dcn = d_in[3];
  const void* b_dcn = d_in[4];
  const void* g1    = d_in[5];
  const void* be1   = d_in[6];
  const void* w_ct  = d_in[7];
  const void* g2    = d_in[8];
  const void* be2   = d_in[9];

  // Workspace: h1 first, then om + weight transposes. 14.16 MB total.
  char* ws = (char*)d_ws;
  unsigned short* h1 = (unsigned short*)(ws + 0);        // 8,388,608 B
  float* om    = (float*)(ws + 8388608);                 // 3,538,944 B
  float* wdcnT = (float*)(ws + 11927552);                // 1,179,648 B
  float* wctT  = (float*)(ws + 13107200);                // 1,048,576 B
  float* woffT = (float*)(ws + 14155776);                //   248,832 B -> ends 14,404,608

  k_detect<<<dim3(1), 256, 0, stream>>>((const unsigned short*)x);
  k_prep<<<dim3(2419), 256, 0, stream>>>(w_dcn, w_ct, w_off, wdcnT, wctT, woffT);
  k_offconv<<<dim3(64, 8), 256, 0, stream>>>(x, b_off, woffT, om);
  k_dcn<<<dim3(64, 8), 256, 0, stream>>>(x, om, wdcnT, b_dcn, h1);
  k_bn1<<<dim3(2048), 256, 0, stream>>>(h1, g1, be1);
  k_ctconv<<<dim3(128, 8), 256, 0, stream>>>(h1, wctT, d_out);
  k_bn2<<<dim3(8192), 256, 0, stream>>>(d_out, g2, be2);
}

// Round 4
// 1112.097 us; speedup vs baseline: 1.1652x; 1.1652x over previous
//
#include <hip/hip_runtime.h>
#include <stdint.h>

// ---------- device globals: dtype flag + BN stats ----------
__device__ int   g_isf32;
__device__ float g_stats[512];  // [0:128) s1sum, [128:256) s1sq, [256:384) s2sum, [384:512) s2sq

typedef __attribute__((ext_vector_type(8))) short bf16x8;
typedef __attribute__((ext_vector_type(4))) float f32x4;

// ---------- bf16 helpers ----------
__device__ __forceinline__ float bf2f(unsigned short u) {
  union { unsigned int i; float f; } v; v.i = ((unsigned int)u) << 16; return v.f;
}
__device__ __forceinline__ unsigned short f2bf(float f) {
  union { float f; unsigned int i; } v; v.f = f;
  unsigned int r = v.i + 0x7FFFu + ((v.i >> 16) & 1u);
  return (unsigned short)(r >> 16);
}
__device__ __forceinline__ unsigned int pk2(float a, float b) {
  return (unsigned int)f2bf(a) | ((unsigned int)f2bf(b) << 16);
}
// dtype-flex input load: f ? fp32 : bf16
__device__ __forceinline__ float ldi(const void* p, size_t i, int f) {
  return f ? ((const float*)p)[i] : bf2f(((const unsigned short*)p)[i]);
}

// ---------- K0: dtype detector + stats zeroing ----------
__global__ void k_detect(const unsigned short* __restrict__ x) {
  __shared__ int cnt;
  const int t = threadIdx.x;
  if (t == 0) cnt = 0;
  g_stats[t] = 0.f; g_stats[t + 256] = 0.f;
  __syncthreads();
  int c = 0;
  for (int j = 0; j < 16; j++) {
    unsigned short u = x[t * 16 + j];
    int e = (u >> 7) & 0xFF;
    if (e == 0xFF || (e != 0 && e <= 100)) c++;
  }
  atomicAdd(&cnt, c);
  __syncthreads();
  if (t == 0) g_isf32 = (cnt > 256) ? 1 : 0;
}

// ---------- K_prep: weights -> GEMM-friendly layouts ----------
// wdcnT[k][c][o] fp32 (9*256*128)   [fallback path]
// wctT[kr][kc][i][o] fp32 (4*4*128*128)
// woffT[ci][k][27] fp32 (256*9*27)
// wdcnA[o][k*256+c] bf16 (128*2304) [MFMA A operand, k-contiguous rows]
__global__ void k_prep(const void* __restrict__ w_dcn, const void* __restrict__ w_ct,
                       const void* __restrict__ w_off,
                       float* __restrict__ wdcnT, float* __restrict__ wctT,
                       float* __restrict__ woffT, unsigned short* __restrict__ wdcnA) {
  const int f = g_isf32;
  int idx = blockIdx.x * 256 + threadIdx.x;
  if (idx < 294912) {
    int k = idx / 32768, c = (idx >> 7) & 255, o = idx & 127;
    wdcnT[idx] = ldi(w_dcn, (size_t)(o * 256 + c) * 9 + k, f);
  }
  int i2 = idx - 294912;
  if (i2 >= 0 && i2 < 262144) {
    int kr = i2 >> 16, kc = (i2 >> 14) & 3, i = (i2 >> 7) & 127, o = i2 & 127;
    wctT[i2] = ldi(w_ct, (size_t)((i * 128 + o) * 4 + kr) * 4 + kc, f);
  }
  int i3 = idx - (294912 + 262144);
  if (i3 >= 0 && i3 < 62208) {
    int ci = i3 / 243, r = i3 - ci * 243, k = r / 27, c = r - (r / 27) * 27;
    woffT[i3] = ldi(w_off, (size_t)(c * 256 + ci) * 9 + k, f);
  }
  int i4 = idx - 619264;
  if (i4 >= 0 && i4 < 294912) {
    int o = i4 / 2304, rem = i4 - o * 2304;
    int k = rem >> 8, c = rem & 255;
    wdcnA[i4] = f2bf(ldi(w_dcn, (size_t)(o * 256 + c) * 9 + k, f));
  }
}

// ---------- K1: 3x3 offset conv, pad 1.  om (8,27,64,64) fp32 ----------
__global__ __launch_bounds__(256) void k_offconv(
    const void* __restrict__ x, const void* __restrict__ b_off,
    const float* __restrict__ woffT, float* __restrict__ om) {
  const int f = g_isf32;
  const int h = blockIdx.x, b = blockIdx.y;
  const int t = threadIdx.x;
  const int cg = t & 31, wg = t >> 5;
  const int w0 = wg * 8;
  __shared__ float xs[32 * 204];   // [ci][3][68], 26112 B
  float acc[8];
#pragma unroll
  for (int i = 0; i < 8; i++) acc[i] = 0.f;

  for (int cb = 0; cb < 256; cb += 32) {
    __syncthreads();
    for (int e = t; e < 32 * 192; e += 256) {
      int ci = e / 192, r = e - ci * 192;
      int dh = r >> 6, w = r & 63;
      int row = h + dh - 1;
      float v = 0.f;
      if (row >= 0 && row < 64)
        v = ldi(x, ((size_t)((b * 256 + cb + ci) * 64 + row) << 6) + w, f);
      xs[ci * 204 + dh * 68 + w + 1] = v;
    }
    for (int e = t; e < 96; e += 256) {
      int base = (e / 3) * 204 + (e - (e / 3) * 3) * 68;
      xs[base] = 0.f; xs[base + 65] = 0.f; xs[base + 66] = 0.f; xs[base + 67] = 0.f;
    }
    __syncthreads();

    for (int ci = 0; ci < 32; ci++) {
      float xr[3][12];
#pragma unroll
      for (int dh = 0; dh < 3; dh++) {
        const float* p = &xs[ci * 204 + dh * 68 + w0];
        float4 q0 = *(const float4*)(p);
        float4 q1 = *(const float4*)(p + 4);
        float4 q2 = *(const float4*)(p + 8);
        xr[dh][0] = q0.x; xr[dh][1] = q0.y; xr[dh][2] = q0.z; xr[dh][3] = q0.w;
        xr[dh][4] = q1.x; xr[dh][5] = q1.y; xr[dh][6] = q1.z; xr[dh][7] = q1.w;
        xr[dh][8] = q2.x; xr[dh][9] = q2.y; xr[dh][10] = q2.z; xr[dh][11] = q2.w;
      }
      if (cg < 27) {
        const float* wp = &woffT[(size_t)(cb + ci) * 243 + cg];
#pragma unroll
        for (int k = 0; k < 9; k++) {
          float wk = wp[k * 27];
          const int dh = k / 3, dx = k - (k / 3) * 3;
#pragma unroll
          for (int wi = 0; wi < 8; wi++)
            acc[wi] = fmaf(wk, xr[dh][wi + dx], acc[wi]);
        }
      }
    }
  }
  if (cg < 27) {
    float bo = ldi(b_off, cg, f);
    float* op = &om[(size_t)((b * 27 + cg) * 64 + h) * 64 + w0];
#pragma unroll
    for (int wi = 0; wi < 8; wi++) op[wi] = acc[wi] + bo;
  }
}

// ---------- K2a: deformable bilinear sampling -> S[b][k*256+c][h*64+w] bf16 ----------
// block = (h, b), 256 threads: lane = w (gathers nearly coalesced), wave = c%4.
__global__ __launch_bounds__(256) void k_sample(
    const void* __restrict__ x, const float* __restrict__ om,
    unsigned short* __restrict__ S) {
  const int f = g_isf32;
  const int h = blockIdx.x, b = blockIdx.y;
  const int t = threadIdx.x;
  const int w = t & 63, wv = t >> 6;
  const float* ob = om + (size_t)(b * 27) * 4096 + h * 64 + w;
  for (int k = 0; k < 9; k++) {
    float oy = ob[(size_t)k * 4096];
    float ox = ob[(size_t)(k + 9) * 4096];
    float mm = ob[(size_t)(k + 18) * 4096];
    float msk = 1.f / (1.f + expf(-mm));
    float py = oy + (float)(h - 1 + k / 3);
    float px = ox + (float)(w - 1 + (k - (k / 3) * 3));
    float y0f = floorf(py), x0f = floorf(px);
    float ly = py - y0f, lx = px - x0f;
    int y0 = (int)y0f, x0 = (int)x0f;
    int y1 = y0 + 1, x1 = x0 + 1;
    float fy0 = (y0 >= 0 && y0 < 64) ? 1.f : 0.f;
    float fy1 = (y1 >= 0 && y1 < 64) ? 1.f : 0.f;
    float fx0 = (x0 >= 0 && x0 < 64) ? 1.f : 0.f;
    float fx1 = (x1 >= 0 && x1 < 64) ? 1.f : 0.f;
    int y0c = min(max(y0, 0), 63), y1c = min(max(y1, 0), 63);
    int x0c = min(max(x0, 0), 63), x1c = min(max(x1, 0), 63);
    int i0 = y0c * 64 + x0c, i1 = y0c * 64 + x1c;
    int i2 = y1c * 64 + x0c, i3 = y1c * 64 + x1c;
    float g0 = (1.f - ly) * (1.f - lx) * msk * fy0 * fx0;
    float g1 = (1.f - ly) * lx * msk * fy0 * fx1;
    float g2 = ly * (1.f - lx) * msk * fy1 * fx0;
    float g3 = ly * lx * msk * fy1 * fx1;
    unsigned short* Sp = S + ((size_t)(b * 9 + k) * 256) * 4096 + h * 64 + w;
    const size_t xb0 = (size_t)b * 256 * 4096;
#pragma unroll 4
    for (int c = wv; c < 256; c += 4) {
      size_t xo = xb0 + (size_t)c * 4096;
      float v = g0 * ldi(x, xo + i0, f) + g1 * ldi(x, xo + i1, f)
              + g2 * ldi(x, xo + i2, f) + g3 * ldi(x, xo + i3, f);
      Sp[(size_t)c * 4096] = f2bf(v);
    }
  }
}

// ---------- K2b: MFMA GEMM  h1[b](128,4096) = wdcnA(128,2304) x S[b](2304,4096) ----------
// 128x128 tile per block, 4 waves in 2x2, each wave 4x4 mfma_f32_16x16x32_bf16.
__global__ __launch_bounds__(256) void k_gemm_dcn(
    const unsigned short* __restrict__ A,   // [128][2304] bf16
    const unsigned short* __restrict__ S,   // [8][2304][4096] bf16
    const void* __restrict__ b_dcn,
    unsigned short* __restrict__ h1) {
  const int f = g_isf32;
  const int nt = blockIdx.x;   // 0..31
  const int b  = blockIdx.y;
  const int t  = threadIdx.x;
  const int wv = t >> 6, L = t & 63;
  const int quad = L >> 4, l15 = L & 15;
  const int wm = (wv >> 1) * 64, wn = (wv & 1) * 64;
  __shared__ unsigned short As[128][40];  // padded: row = 80 B (16B-mult)
  __shared__ unsigned short Bs[128][40];  // transposed: Bs[n][k]
  f32x4 acc[4][4] = {};
  const unsigned short* Sb = S + (size_t)b * 2304 * 4096 + (size_t)nt * 128;

  for (int kk = 0; kk < 2304; kk += 32) {
    __syncthreads();
    {   // stage A-tile 128x32: t -> (m = t>>1, seg = t&1)
      int m = t >> 1, seg = t & 1;
      const unsigned short* ap = A + (size_t)m * 2304 + kk + seg * 16;
      uint4 q0 = *(const uint4*)(ap);
      uint4 q1 = *(const uint4*)(ap + 8);
      *(uint4*)&As[m][seg * 16]     = q0;
      *(uint4*)&As[m][seg * 16 + 8] = q1;
    }
    {   // stage B-tile 32x128 transposed: t -> (kr = t>>3, oct = t&7)
      int kr = t >> 3, oct = t & 7;
      const unsigned short* bp = Sb + (size_t)(kk + kr) * 4096 + oct * 16;
      uint4 q0 = *(const uint4*)(bp);
      uint4 q1 = *(const uint4*)(bp + 8);
      unsigned short e[16];
      *(uint4*)&e[0] = q0; *(uint4*)&e[8] = q1;
#pragma unroll
      for (int j = 0; j < 16; j++) Bs[oct * 16 + j][kr] = e[j];
    }
    __syncthreads();
    const int ar = quad * 8;
    bf16x8 af[4], bfr[4];
#pragma unroll
    for (int tm = 0; tm < 4; tm++) af[tm]  = *(const bf16x8*)&As[wm + tm * 16 + l15][ar];
#pragma unroll
    for (int tn = 0; tn < 4; tn++) bfr[tn] = *(const bf16x8*)&Bs[wn + tn * 16 + l15][ar];
#pragma unroll
    for (int tm = 0; tm < 4; tm++)
#pragma unroll
      for (int tn = 0; tn < 4; tn++)
        acc[tm][tn] = __builtin_amdgcn_mfma_f32_16x16x32_bf16(af[tm], bfr[tn], acc[tm][tn], 0, 0, 0);
  }

  // epilogue: bias + bf16 h1 store + per-channel stats
#pragma unroll
  for (int tm = 0; tm < 4; tm++) {
#pragma unroll
    for (int r = 0; r < 4; r++) {
      int m = wm + tm * 16 + quad * 4 + r;
      float bd = ldi(b_dcn, m, f);
      float s = 0.f, q = 0.f;
#pragma unroll
      for (int tn = 0; tn < 4; tn++) {
        float v = acc[tm][tn][r] + bd;
        int n = nt * 128 + wn + tn * 16 + l15;
        h1[(size_t)(b * 128 + m) * 4096 + n] = f2bf(v);
        s += v; q += v * v;
      }
#pragma unroll
      for (int msk = 1; msk < 16; msk <<= 1) {
        s += __shfl_xor(s, msk, 64);
        q += __shfl_xor(q, msk, 64);
      }
      if (l15 == 0) { atomicAdd(&g_stats[m], s); atomicAdd(&g_stats[128 + m], q); }
    }
  }
}

// ---------- K2 fallback (round-3): fused sampling + fp32 GEMM ----------
__global__ __launch_bounds__(256) void k_dcn(
    const void* __restrict__ x, const float* __restrict__ om,
    const float* __restrict__ wdcnT, const void* __restrict__ b_dcn,
    unsigned short* __restrict__ h1) {
  const int f = g_isf32;
  const int h = blockIdx.x, b = blockIdx.y;
  const int t = threadIdx.x;
  __shared__ float S[64 * 64];
  __shared__ int   midx[64][4];
  __shared__ float mwgt[64][4];
  const int og = t >> 4, pg = t & 15;
  const int pA = t & 63, cgA = t >> 6;
  float acc[8][4];
#pragma unroll
  for (int j = 0; j < 8; j++)
#pragma unroll
    for (int i = 0; i < 4; i++) acc[j][i] = 0.f;

  for (int k = 0; k < 9; k++) {
    if (t < 64) {
      const int w = t;
      const float* ob = &om[(size_t)(b * 27) * 4096 + h * 64 + w];
      float oy = ob[(size_t)k * 4096];
      float ox = ob[(size_t)(k + 9) * 4096];
      float mm = ob[(size_t)(k + 18) * 4096];
      float msk = 1.f / (1.f + expf(-mm));
      float py = oy + (float)(h - 1 + k / 3);
      float px = ox + (float)(w - 1 + (k - (k / 3) * 3));
      float y0f = floorf(py), x0f = floorf(px);
      float ly = py - y0f, lx = px - x0f;
      int y0 = (int)y0f, x0 = (int)x0f;
      int y1 = y0 + 1, x1 = x0 + 1;
      float fy0 = (y0 >= 0 && y0 < 64) ? 1.f : 0.f;
      float fy1 = (y1 >= 0 && y1 < 64) ? 1.f : 0.f;
      float fx0 = (x0 >= 0 && x0 < 64) ? 1.f : 0.f;
      float fx1 = (x1 >= 0 && x1 < 64) ? 1.f : 0.f;
      int y0c = min(max(y0, 0), 63), y1c = min(max(y1, 0), 63);
      int x0c = min(max(x0, 0), 63), x1c = min(max(x1, 0), 63);
      midx[w][0] = y0c * 64 + x0c;
      midx[w][1] = y0c * 64 + x1c;
      midx[w][2] = y1c * 64 + x0c;
      midx[w][3] = y1c * 64 + x1c;
      mwgt[w][0] = (1.f - ly) * (1.f - lx) * msk * fy0 * fx0;
      mwgt[w][1] = (1.f - ly) * lx * msk * fy0 * fx1;
      mwgt[w][2] = ly * (1.f - lx) * msk * fy1 * fx0;
      mwgt[w][3] = ly * lx * msk * fy1 * fx1;
    }
    for (int ch = 0; ch < 4; ch++) {
      __syncthreads();
      {
        const int i0 = midx[pA][0], i1 = midx[pA][1], i2 = midx[pA][2], i3 = midx[pA][3];
        const float g0 = mwgt[pA][0], g1 = mwgt[pA][1], g2 = mwgt[pA][2], g3 = mwgt[pA][3];
        const size_t cbase = (size_t)(b * 256 + ch * 64 + cgA * 16) * 4096;
        float* Sp = &S[(cgA * 16) * 64 + pA];
#pragma unroll 4
        for (int j = 0; j < 16; j++) {
          const size_t xo = cbase + (size_t)j * 4096;
          float v = g0 * ldi(x, xo + i0, f) + g1 * ldi(x, xo + i1, f)
                  + g2 * ldi(x, xo + i2, f) + g3 * ldi(x, xo + i3, f);
          Sp[j * 64] = v;
        }
      }
      __syncthreads();
      const float* wk = wdcnT + (size_t)k * 32768 + (size_t)(ch * 64) * 128;
#pragma unroll 2
      for (int c2 = 0; c2 < 64; c2++) {
        float4 a0 = *(const float4*)&wk[c2 * 128 + og * 8];
        float4 a1 = *(const float4*)&wk[c2 * 128 + og * 8 + 4];
        float4 s4 = *(const float4*)&S[c2 * 64 + pg * 4];
        float aa[8] = {a0.x, a0.y, a0.z, a0.w, a1.x, a1.y, a1.z, a1.w};
        float ss[4] = {s4.x, s4.y, s4.z, s4.w};
#pragma unroll
        for (int j = 0; j < 8; j++)
#pragma unroll
          for (int i = 0; i < 4; i++)
            acc[j][i] = fmaf(aa[j], ss[i], acc[j][i]);
      }
    }
  }
#pragma unroll
  for (int j = 0; j < 8; j++) {
    const int o = og * 8 + j;
    float bd = ldi(b_dcn, o, f);
    float v0 = acc[j][0] + bd, v1 = acc[j][1] + bd, v2 = acc[j][2] + bd, v3 = acc[j][3] + bd;
    float s = v0 + v1 + v2 + v3;
    float q = v0 * v0 + v1 * v1 + v2 * v2 + v3 * v3;
    uint2 pkv = make_uint2(pk2(v0, v1), pk2(v2, v3));
    *(uint2*)(h1 + (size_t)((b * 128 + o) * 64 + h) * 64 + pg * 4) = pkv;
#pragma unroll
    for (int m = 1; m < 16; m <<= 1) {
      s += __shfl_xor(s, m, 64);
      q += __shfl_xor(q, m, 64);
    }
    if (pg == 0) { atomicAdd(&g_stats[o], s); atomicAdd(&g_stats[128 + o], q); }
  }
}

// ---------- K3: BN1 + ReLU in place on h1 (bf16 internal) ----------
__global__ void k_bn1(unsigned short* __restrict__ h1, const void* __restrict__ g1,
                      const void* __restrict__ be1) {
  const int f = g_isf32;
  int gid = blockIdx.x * 256 + threadIdx.x;
  size_t base = (size_t)gid * 8;
  int o = (int)((base >> 12) & 127);
  float mu = g_stats[o] * (1.f / 32768.f);
  float var = g_stats[128 + o] * (1.f / 32768.f) - mu * mu;
  float sc = rsqrtf(var + 1e-5f) * ldi(g1, o, f);
  float sh = ldi(be1, o, f) - mu * sc;
  uint4 p = *(const uint4*)(h1 + base);
  unsigned int pp[4] = {p.x, p.y, p.z, p.w};
  unsigned int r[4];
#pragma unroll
  for (int i = 0; i < 4; i++) {
    float f0 = fmaxf(fmaf(bf2f((unsigned short)(pp[i] & 0xffff)), sc, sh), 0.f);
    float f1 = fmaxf(fmaf(bf2f((unsigned short)(pp[i] >> 16)), sc, sh), 0.f);
    r[i] = pk2(f0, f1);
  }
  *(uint4*)(h1 + base) = make_uint4(r[0], r[1], r[2], r[3]);
}

// ---------- K4: 4x4 stride-2 transposed conv (parity 2x2 taps) + stats ----------
__global__ __launch_bounds__(256) void k_ctconv(
    const unsigned short* __restrict__ h1n, const float* __restrict__ wctT,
    void* __restrict__ out2) {
  const int f = g_isf32;
  const int y = blockIdx.x, b = blockIdx.y;
  const int t = threadIdx.x;
  const int og = t >> 3, xg = t & 7;
  __shared__ float hs[2 * 32 * 68];   // 17408 B
  int kr0, kr1, r0, r1;
  if ((y & 1) == 0) { kr0 = 1; r0 = y >> 1; kr1 = 3; r1 = (y >> 1) - 1; }
  else              { kr0 = 0; r0 = (y + 1) >> 1; kr1 = 2; r1 = (y - 1) >> 1; }
  float acc[4][16];
#pragma unroll
  for (int j = 0; j < 4; j++)
#pragma unroll
    for (int i = 0; i < 16; i++) acc[j][i] = 0.f;

  for (int ihc = 0; ihc < 4; ihc++) {
    __syncthreads();
    for (int e = t; e < 2 * 32 * 64; e += 256) {
      int rr = e >> 11, rem = e & 2047, il = rem >> 6, w = rem & 63;
      int i = ihc * 32 + il;
      int row = rr ? r1 : r0;
      float v = 0.f;
      if (row >= 0 && row < 64)
        v = bf2f(h1n[(size_t)((b * 128 + i) * 64 + row) * 64 + w]);
      hs[(rr * 32 + il) * 68 + w + 1] = v;
    }
    for (int e = t; e < 64; e += 256) {
      int base = e * 68;
      hs[base] = 0.f; hs[base + 65] = 0.f; hs[base + 66] = 0.f; hs[base + 67] = 0.f;
    }
    __syncthreads();
    for (int il = 0; il < 32; il++) {
      const int i = ihc * 32 + il;
      float br[2][12];
#pragma unroll
      for (int rr = 0; rr < 2; rr++) {
        const float* p = &hs[(rr * 32 + il) * 68 + xg * 8];
        float4 q0 = *(const float4*)(p);
        float4 q1 = *(const float4*)(p + 4);
        float4 q2 = *(const float4*)(p + 8);
        br[rr][0] = q0.x; br[rr][1] = q0.y; br[rr][2] = q0.z; br[rr][3] = q0.w;
        br[rr][4] = q1.x; br[rr][5] = q1.y; br[rr][6] = q1.z; br[rr][7] = q1.w;
        br[rr][8] = q2.x; br[rr][9] = q2.y; br[rr][10] = q2.z; br[rr][11] = q2.w;
      }
      float a[2][4][4];
#pragma unroll
      for (int rr = 0; rr < 2; rr++) {
        const int krr = rr ? kr1 : kr0;
#pragma unroll
        for (int kc = 0; kc < 4; kc++) {
          float4 av = *(const float4*)&wctT[((size_t)(krr * 4 + kc) * 128 + i) * 128 + og * 4];
          a[rr][kc][0] = av.x; a[rr][kc][1] = av.y; a[rr][kc][2] = av.z; a[rr][kc][3] = av.w;
        }
      }
#pragma unroll
      for (int xi = 0; xi < 16; xi++) {
        const int u = xi >> 1;
        const int kcA = (xi & 1) ? 0 : 1;
        const int lwA = (xi & 1) ? u + 2 : u + 1;
        const int kcB = (xi & 1) ? 2 : 3;
        const int lwB = (xi & 1) ? u + 1 : u;
#pragma unroll
        for (int rr = 0; rr < 2; rr++) {
#pragma unroll
          for (int j = 0; j < 4; j++) {
            acc[j][xi] = fmaf(a[rr][kcA][j], br[rr][lwA], acc[j][xi]);
            acc[j][xi] = fmaf(a[rr][kcB][j], br[rr][lwB], acc[j][xi]);
          }
        }
      }
    }
  }
#pragma unroll
  for (int j = 0; j < 4; j++) {
    const int o = og * 4 + j;
    float s = 0.f, q = 0.f;
#pragma unroll
    for (int xi = 0; xi < 16; xi++) { s += acc[j][xi]; q += acc[j][xi] * acc[j][xi]; }
    size_t ofs = (size_t)((b * 128 + o) * 128 + y) * 128 + xg * 16;
    if (f) {
      float* op = (float*)out2 + ofs;
#pragma unroll
      for (int v4 = 0; v4 < 4; v4++)
        ((float4*)op)[v4] = make_float4(acc[j][4 * v4], acc[j][4 * v4 + 1],
                                        acc[j][4 * v4 + 2], acc[j][4 * v4 + 3]);
    } else {
      unsigned int w_[8];
#pragma unroll
      for (int xi = 0; xi < 8; xi++) w_[xi] = pk2(acc[j][2 * xi], acc[j][2 * xi + 1]);
      unsigned short* op = (unsigned short*)out2 + ofs;
      *(uint4*)(op)     = make_uint4(w_[0], w_[1], w_[2], w_[3]);
      *(uint4*)(op + 8) = make_uint4(w_[4], w_[5], w_[6], w_[7]);
    }
#pragma unroll
    for (int m = 1; m < 8; m <<= 1) {
      s += __shfl_xor(s, m, 64);
      q += __shfl_xor(q, m, 64);
    }
    if (xg == 0) { atomicAdd(&g_stats[256 + o], s); atomicAdd(&g_stats[384 + o], q); }
  }
}

// ---------- K5: BN2 + ReLU in place on d_out ----------
__global__ void k_bn2(void* __restrict__ out2, const void* __restrict__ g2,
                      const void* __restrict__ be2) {
  const int f = g_isf32;
  int gid = blockIdx.x * 256 + threadIdx.x;
  size_t base = (size_t)gid * 8;
  int o = (int)((base >> 14) & 127);
  float mu = g_stats[256 + o] * (1.f / 131072.f);
  float var = g_stats[384 + o] * (1.f / 131072.f) - mu * mu;
  float sc = rsqrtf(var + 1e-5f) * ldi(g2, o, f);
  float sh = ldi(be2, o, f) - mu * sc;
  if (f) {
    float4* op = (float4*)out2 + gid * 2;
    float4 p0 = op[0], p1 = op[1];
    p0.x = fmaxf(fmaf(p0.x, sc, sh), 0.f); p0.y = fmaxf(fmaf(p0.y, sc, sh), 0.f);
    p0.z = fmaxf(fmaf(p0.z, sc, sh), 0.f); p0.w = fmaxf(fmaf(p0.w, sc, sh), 0.f);
    p1.x = fmaxf(fmaf(p1.x, sc, sh), 0.f); p1.y = fmaxf(fmaf(p1.y, sc, sh), 0.f);
    p1.z = fmaxf(fmaf(p1.z, sc, sh), 0.f); p1.w = fmaxf(fmaf(p1.w, sc, sh), 0.f);
    op[0] = p0; op[1] = p1;
  } else {
    unsigned short* ob = (unsigned short*)out2 + base;
    uint4 p = *(const uint4*)ob;
    unsigned int pp[4] = {p.x, p.y, p.z, p.w};
    unsigned int r[4];
#pragma unroll
    for (int i = 0; i < 4; i++) {
      float f0 = fmaxf(fmaf(bf2f((unsigned short)(pp[i] & 0xffff)), sc, sh), 0.f);
      float f1 = fmaxf(fmaf(bf2f((unsigned short)(pp[i] >> 16)), sc, sh), 0.f);
      r[i] = pk2(f0, f1);
    }
    *(uint4*)ob = make_uint4(r[0], r[1], r[2], r[3]);
  }
}

// ---------- launch ----------
extern "C" void kernel_launch(void* const* d_in, const int* in_sizes, int n_in,
                              void* d_out, int out_size, void* d_ws, size_t ws_size,
                              hipStream_t stream) {
  const void* x     = d_in[0];
  const void* w_off = d_in[1];
  const void* b_off = d_in[2];
  const void* w_dcn = d_in[3];
  const void* b_dcn = d_in[4];
  const void* g1    = d_in[5];
  const void* be1   = d_in[6];
  const void* w_ct  = d_in[7];
  const void* g2    = d_in[8];
  const void* be2   = d_in[9];

  char* ws = (char*)d_ws;
  const bool fast = ws_size >= (size_t)166000000;

  unsigned short* Sbuf; unsigned short* h1; float* om; float* wdcnT; float* wctT;
  float* woffT; unsigned short* wdcnA;
  if (fast) {
    Sbuf  = (unsigned short*)(ws + 0);            // 150,994,944 B
    h1    = (unsigned short*)(ws + 150994944);    //   8,388,608 B
    om    = (float*)(ws + 159383552);             //   3,538,944 B
    wdcnT = (float*)(ws + 162922496);             //   1,179,648 B
    wctT  = (float*)(ws + 164102144);             //   1,048,576 B
    woffT = (float*)(ws + 165150720);             //     248,832 B
    wdcnA = (unsigned short*)(ws + 165399552);    //     589,824 B -> 165,989,376
  } else {
    Sbuf  = nullptr;
    h1    = (unsigned short*)(ws + 0);            //   8,388,608 B
    om    = (float*)(ws + 8388608);               //   3,538,944 B
    wdcnT = (float*)(ws + 11927552);              //   1,179,648 B
    wctT  = (float*)(ws + 13107200);              //   1,048,576 B
    woffT = (float*)(ws + 14155776);              //     248,832 B
    wdcnA = (unsigned short*)(ws + 14404608);     //     589,824 B -> 14,994,432
  }

  k_detect<<<dim3(1), 256, 0, stream>>>((const unsigned short*)x);
  k_prep<<<dim3(3571), 256, 0, stream>>>(w_dcn, w_ct, w_off, wdcnT, wctT, woffT, wdcnA);
  k_offconv<<<dim3(64, 8), 256, 0, stream>>>(x, b_off, woffT, om);
  if (fast) {
    k_sample<<<dim3(64, 8), 256, 0, stream>>>(x, om, Sbuf);
    k_gemm_dcn<<<dim3(32, 8), 256, 0, stream>>>(wdcnA, Sbuf, b_dcn, h1);
  } else {
    k_dcn<<<dim3(64, 8), 256, 0, stream>>>(x, om, wdcnT, b_dcn, h1);
  }
  k_bn1<<<dim3(2048), 256, 0, stream>>>(h1, g1, be1);
  k_ctconv<<<dim3(128, 8), 256, 0, stream>>>(h1, wctT, d_out);
  k_bn2<<<dim3(8192), 256, 0, stream>>>(d_out, g2, be2);
}

// Round 5
// 949.802 us; speedup vs baseline: 1.3643x; 1.1709x over previous
//
#include <hip/hip_runtime.h>
#include <stdint.h>

// ---------- device globals: dtype flag + BN stats ----------
__device__ int   g_isf32;
__device__ float g_stats[512];  // [0:128) s1sum, [128:256) s1sq, [256:384) s2sum, [384:512) s2sq

typedef __attribute__((ext_vector_type(8))) short bf16x8;
typedef __attribute__((ext_vector_type(4))) float f32x4;

// ---------- bf16 helpers ----------
__device__ __forceinline__ float bf2f(unsigned short u) {
  union { unsigned int i; float f; } v; v.i = ((unsigned int)u) << 16; return v.f;
}
__device__ __forceinline__ unsigned short f2bf(float f) {
  union { float f; unsigned int i; } v; v.f = f;
  unsigned int r = v.i + 0x7FFFu + ((v.i >> 16) & 1u);
  return (unsigned short)(r >> 16);
}
__device__ __forceinline__ unsigned int pk2(float a, float b) {
  return (unsigned int)f2bf(a) | ((unsigned int)f2bf(b) << 16);
}
// dtype-flex input load: f ? fp32 : bf16
__device__ __forceinline__ float ldi(const void* p, size_t i, int f) {
  return f ? ((const float*)p)[i] : bf2f(((const unsigned short*)p)[i]);
}

// ---------- K0: dtype detector + stats zeroing ----------
__global__ void k_detect(const unsigned short* __restrict__ x) {
  __shared__ int cnt;
  const int t = threadIdx.x;
  if (t == 0) cnt = 0;
  g_stats[t] = 0.f; g_stats[t + 256] = 0.f;
  __syncthreads();
  int c = 0;
  for (int j = 0; j < 16; j++) {
    unsigned short u = x[t * 16 + j];
    int e = (u >> 7) & 0xFF;
    if (e == 0xFF || (e != 0 && e <= 100)) c++;
  }
  atomicAdd(&cnt, c);
  __syncthreads();
  if (t == 0) g_isf32 = (cnt > 256) ? 1 : 0;
}

// ---------- K_prep: weights -> GEMM-friendly layouts ----------
__global__ void k_prep(const void* __restrict__ w_dcn, const void* __restrict__ w_ct,
                       const void* __restrict__ w_off,
                       float* __restrict__ wdcnT, float* __restrict__ wctT,
                       float* __restrict__ woffT, unsigned short* __restrict__ wdcnA) {
  const int f = g_isf32;
  int idx = blockIdx.x * 256 + threadIdx.x;
  if (idx < 294912) {
    int k = idx / 32768, c = (idx >> 7) & 255, o = idx & 127;
    wdcnT[idx] = ldi(w_dcn, (size_t)(o * 256 + c) * 9 + k, f);
  }
  int i2 = idx - 294912;
  if (i2 >= 0 && i2 < 262144) {
    int kr = i2 >> 16, kc = (i2 >> 14) & 3, i = (i2 >> 7) & 127, o = i2 & 127;
    wctT[i2] = ldi(w_ct, (size_t)((i * 128 + o) * 4 + kr) * 4 + kc, f);
  }
  int i3 = idx - (294912 + 262144);
  if (i3 >= 0 && i3 < 62208) {
    int ci = i3 / 243, r = i3 - ci * 243, k = r / 27, c = r - (r / 27) * 27;
    woffT[i3] = ldi(w_off, (size_t)(c * 256 + ci) * 9 + k, f);
  }
  int i4 = idx - 619264;
  if (i4 >= 0 && i4 < 294912) {
    int o = i4 / 2304, rem = i4 - o * 2304;
    int k = rem >> 8, c = rem & 255;
    wdcnA[i4] = f2bf(ldi(w_dcn, (size_t)(o * 256 + c) * 9 + k, f));
  }
}

// ---------- K_prep2: parity-decomposed ct-conv A matrices (fast path only) ----------
// Apar[par][o][tap*128 + i] bf16, par = py*2+px, tap = a*2+b
// kr(py,a): py0 -> {1,3}, py1 -> {0,2};  kc(px,b) analogous.
__global__ void k_prep2(const float* __restrict__ wctT, unsigned short* __restrict__ Apar) {
  int idx = blockIdx.x * 256 + threadIdx.x;   // 262144
  int par = idx >> 16, rem = idx & 65535;
  int o = rem >> 9, rem2 = rem & 511;
  int tap = rem2 >> 7, i = rem2 & 127;
  int py = par >> 1, px = par & 1, a = tap >> 1, bb = tap & 1;
  int kr = (py == 0) ? (a ? 3 : 1) : (a ? 2 : 0);
  int kc = (px == 0) ? (bb ? 3 : 1) : (bb ? 2 : 0);
  Apar[idx] = f2bf(wctT[((size_t)(kr * 4 + kc) * 128 + i) * 128 + o]);
}

// ---------- K1: 3x3 offset conv, pad 1.  om (8,27,64,64) fp32 ----------
__global__ __launch_bounds__(256) void k_offconv(
    const void* __restrict__ x, const void* __restrict__ b_off,
    const float* __restrict__ woffT, float* __restrict__ om) {
  const int f = g_isf32;
  const int h = blockIdx.x, b = blockIdx.y;
  const int t = threadIdx.x;
  const int cg = t & 31, wg = t >> 5;
  const int w0 = wg * 8;
  __shared__ float xs[32 * 204];
  float acc[8];
#pragma unroll
  for (int i = 0; i < 8; i++) acc[i] = 0.f;

  for (int cb = 0; cb < 256; cb += 32) {
    __syncthreads();
    for (int e = t; e < 32 * 192; e += 256) {
      int ci = e / 192, r = e - ci * 192;
      int dh = r >> 6, w = r & 63;
      int row = h + dh - 1;
      float v = 0.f;
      if (row >= 0 && row < 64)
        v = ldi(x, ((size_t)((b * 256 + cb + ci) * 64 + row) << 6) + w, f);
      xs[ci * 204 + dh * 68 + w + 1] = v;
    }
    for (int e = t; e < 96; e += 256) {
      int base = (e / 3) * 204 + (e - (e / 3) * 3) * 68;
      xs[base] = 0.f; xs[base + 65] = 0.f; xs[base + 66] = 0.f; xs[base + 67] = 0.f;
    }
    __syncthreads();

    for (int ci = 0; ci < 32; ci++) {
      float xr[3][12];
#pragma unroll
      for (int dh = 0; dh < 3; dh++) {
        const float* p = &xs[ci * 204 + dh * 68 + w0];
        float4 q0 = *(const float4*)(p);
        float4 q1 = *(const float4*)(p + 4);
        float4 q2 = *(const float4*)(p + 8);
        xr[dh][0] = q0.x; xr[dh][1] = q0.y; xr[dh][2] = q0.z; xr[dh][3] = q0.w;
        xr[dh][4] = q1.x; xr[dh][5] = q1.y; xr[dh][6] = q1.z; xr[dh][7] = q1.w;
        xr[dh][8] = q2.x; xr[dh][9] = q2.y; xr[dh][10] = q2.z; xr[dh][11] = q2.w;
      }
      if (cg < 27) {
        const float* wp = &woffT[(size_t)(cb + ci) * 243 + cg];
#pragma unroll
        for (int k = 0; k < 9; k++) {
          float wk = wp[k * 27];
          const int dh = k / 3, dx = k - (k / 3) * 3;
#pragma unroll
          for (int wi = 0; wi < 8; wi++)
            acc[wi] = fmaf(wk, xr[dh][wi + dx], acc[wi]);
        }
      }
    }
  }
  if (cg < 27) {
    float bo = ldi(b_off, cg, f);
    float* op = &om[(size_t)((b * 27 + cg) * 64 + h) * 64 + w0];
#pragma unroll
    for (int wi = 0; wi < 8; wi++) op[wi] = acc[wi] + bo;
  }
}

// ---------- K2a: deformable bilinear sampling -> S[b][k*256+c][h*64+w] bf16 ----------
// grid (h, b, cq): 2048 blocks for occupancy; each handles 64 channels.
__global__ __launch_bounds__(256) void k_sample(
    const void* __restrict__ x, const float* __restrict__ om,
    unsigned short* __restrict__ S) {
  const int f = g_isf32;
  const int h = blockIdx.x, b = blockIdx.y, cq = blockIdx.z;
  const int t = threadIdx.x;
  const int w = t & 63, wv = t >> 6;
  const int c0 = cq * 64;
  const float* ob = om + (size_t)(b * 27) * 4096 + h * 64 + w;
  for (int k = 0; k < 9; k++) {
    float oy = ob[(size_t)k * 4096];
    float ox = ob[(size_t)(k + 9) * 4096];
    float mm = ob[(size_t)(k + 18) * 4096];
    float msk = 1.f / (1.f + expf(-mm));
    float py = oy + (float)(h - 1 + k / 3);
    float px = ox + (float)(w - 1 + (k - (k / 3) * 3));
    float y0f = floorf(py), x0f = floorf(px);
    float ly = py - y0f, lx = px - x0f;
    int y0 = (int)y0f, x0 = (int)x0f;
    int y1 = y0 + 1, x1 = x0 + 1;
    float fy0 = (y0 >= 0 && y0 < 64) ? 1.f : 0.f;
    float fy1 = (y1 >= 0 && y1 < 64) ? 1.f : 0.f;
    float fx0 = (x0 >= 0 && x0 < 64) ? 1.f : 0.f;
    float fx1 = (x1 >= 0 && x1 < 64) ? 1.f : 0.f;
    int y0c = min(max(y0, 0), 63), y1c = min(max(y1, 0), 63);
    int x0c = min(max(x0, 0), 63), x1c = min(max(x1, 0), 63);
    int i0 = y0c * 64 + x0c, i1 = y0c * 64 + x1c;
    int i2 = y1c * 64 + x0c, i3 = y1c * 64 + x1c;
    float g0 = (1.f - ly) * (1.f - lx) * msk * fy0 * fx0;
    float g1 = (1.f - ly) * lx * msk * fy0 * fx1;
    float g2 = ly * (1.f - lx) * msk * fy1 * fx0;
    float g3 = ly * lx * msk * fy1 * fx1;
    unsigned short* Sp = S + ((size_t)(b * 9 + k) * 256) * 4096 + h * 64 + w;
    const size_t xb0 = (size_t)b * 256 * 4096;
#pragma unroll 4
    for (int c = c0 + wv; c < c0 + 64; c += 4) {
      size_t xo = xb0 + (size_t)c * 4096;
      float v = g0 * ldi(x, xo + i0, f) + g1 * ldi(x, xo + i1, f)
              + g2 * ldi(x, xo + i2, f) + g3 * ldi(x, xo + i3, f);
      Sp[(size_t)c * 4096] = f2bf(v);
    }
  }
}

// ---------- K2b: MFMA GEMM  h1[b](128,4096) = wdcnA(128,2304) x S[b](2304,4096) ----------
__global__ __launch_bounds__(256) void k_gemm_dcn(
    const unsigned short* __restrict__ A,   // [128][2304] bf16
    const unsigned short* __restrict__ S,   // [8][2304][4096] bf16
    const void* __restrict__ b_dcn,
    unsigned short* __restrict__ h1) {
  const int f = g_isf32;
  const int nt = blockIdx.x;   // 0..31
  const int b  = blockIdx.y;
  const int t  = threadIdx.x;
  const int wv = t >> 6, L = t & 63;
  const int quad = L >> 4, l15 = L & 15;
  const int wm = (wv >> 1) * 64, wn = (wv & 1) * 64;
  __shared__ unsigned short As[128][40];
  __shared__ unsigned short Bs[128][40];
  f32x4 acc[4][4] = {};
  const unsigned short* Sb = S + (size_t)b * 2304 * 4096 + (size_t)nt * 128;

  for (int kk = 0; kk < 2304; kk += 32) {
    __syncthreads();
    {   // stage A-tile 128x32
      int m = t >> 1, seg = t & 1;
      const unsigned short* ap = A + (size_t)m * 2304 + kk + seg * 16;
      uint4 q0 = *(const uint4*)(ap);
      uint4 q1 = *(const uint4*)(ap + 8);
      *(uint4*)&As[m][seg * 16]     = q0;
      *(uint4*)&As[m][seg * 16 + 8] = q1;
    }
    {   // stage B-tile 32x128 transposed; kr fast in lane -> <=2-way LDS conflicts
      int kr = t & 31, oct = t >> 5;
      const unsigned short* bp = Sb + (size_t)(kk + kr) * 4096 + oct * 16;
      uint4 q0 = *(const uint4*)(bp);
      uint4 q1 = *(const uint4*)(bp + 8);
      unsigned short e[16];
      *(uint4*)&e[0] = q0; *(uint4*)&e[8] = q1;
#pragma unroll
      for (int j = 0; j < 16; j++) Bs[oct * 16 + j][kr] = e[j];
    }
    __syncthreads();
    const int ar = quad * 8;
    bf16x8 af[4], bfr[4];
#pragma unroll
    for (int tm = 0; tm < 4; tm++) af[tm]  = *(const bf16x8*)&As[wm + tm * 16 + l15][ar];
#pragma unroll
    for (int tn = 0; tn < 4; tn++) bfr[tn] = *(const bf16x8*)&Bs[wn + tn * 16 + l15][ar];
#pragma unroll
    for (int tm = 0; tm < 4; tm++)
#pragma unroll
      for (int tn = 0; tn < 4; tn++)
        acc[tm][tn] = __builtin_amdgcn_mfma_f32_16x16x32_bf16(af[tm], bfr[tn], acc[tm][tn], 0, 0, 0);
  }

#pragma unroll
  for (int tm = 0; tm < 4; tm++) {
#pragma unroll
    for (int r = 0; r < 4; r++) {
      int m = wm + tm * 16 + quad * 4 + r;
      float bd = ldi(b_dcn, m, f);
      float s = 0.f, q = 0.f;
#pragma unroll
      for (int tn = 0; tn < 4; tn++) {
        float v = acc[tm][tn][r] + bd;
        int n = nt * 128 + wn + tn * 16 + l15;
        h1[(size_t)(b * 128 + m) * 4096 + n] = f2bf(v);
        s += v; q += v * v;
      }
#pragma unroll
      for (int msk = 1; msk < 16; msk <<= 1) {
        s += __shfl_xor(s, msk, 64);
        q += __shfl_xor(q, msk, 64);
      }
      if (l15 == 0) { atomicAdd(&g_stats[m], s); atomicAdd(&g_stats[128 + m], q); }
    }
  }
}

// ---------- K2 fallback: fused sampling + fp32 GEMM ----------
__global__ __launch_bounds__(256) void k_dcn(
    const void* __restrict__ x, const float* __restrict__ om,
    const float* __restrict__ wdcnT, const void* __restrict__ b_dcn,
    unsigned short* __restrict__ h1) {
  const int f = g_isf32;
  const int h = blockIdx.x, b = blockIdx.y;
  const int t = threadIdx.x;
  __shared__ float S[64 * 64];
  __shared__ int   midx[64][4];
  __shared__ float mwgt[64][4];
  const int og = t >> 4, pg = t & 15;
  const int pA = t & 63, cgA = t >> 6;
  float acc[8][4];
#pragma unroll
  for (int j = 0; j < 8; j++)
#pragma unroll
    for (int i = 0; i < 4; i++) acc[j][i] = 0.f;

  for (int k = 0; k < 9; k++) {
    if (t < 64) {
      const int w = t;
      const float* ob = &om[(size_t)(b * 27) * 4096 + h * 64 + w];
      float oy = ob[(size_t)k * 4096];
      float ox = ob[(size_t)(k + 9) * 4096];
      float mm = ob[(size_t)(k + 18) * 4096];
      float msk = 1.f / (1.f + expf(-mm));
      float py = oy + (float)(h - 1 + k / 3);
      float px = ox + (float)(w - 1 + (k - (k / 3) * 3));
      float y0f = floorf(py), x0f = floorf(px);
      float ly = py - y0f, lx = px - x0f;
      int y0 = (int)y0f, x0 = (int)x0f;
      int y1 = y0 + 1, x1 = x0 + 1;
      float fy0 = (y0 >= 0 && y0 < 64) ? 1.f : 0.f;
      float fy1 = (y1 >= 0 && y1 < 64) ? 1.f : 0.f;
      float fx0 = (x0 >= 0 && x0 < 64) ? 1.f : 0.f;
      float fx1 = (x1 >= 0 && x1 < 64) ? 1.f : 0.f;
      int y0c = min(max(y0, 0), 63), y1c = min(max(y1, 0), 63);
      int x0c = min(max(x0, 0), 63), x1c = min(max(x1, 0), 63);
      midx[w][0] = y0c * 64 + x0c;
      midx[w][1] = y0c * 64 + x1c;
      midx[w][2] = y1c * 64 + x0c;
      midx[w][3] = y1c * 64 + x1c;
      mwgt[w][0] = (1.f - ly) * (1.f - lx) * msk * fy0 * fx0;
      mwgt[w][1] = (1.f - ly) * lx * msk * fy0 * fx1;
      mwgt[w][2] = ly * (1.f - lx) * msk * fy1 * fx0;
      mwgt[w][3] = ly * lx * msk * fy1 * fx1;
    }
    for (int ch = 0; ch < 4; ch++) {
      __syncthreads();
      {
        const int i0 = midx[pA][0], i1 = midx[pA][1], i2 = midx[pA][2], i3 = midx[pA][3];
        const float g0 = mwgt[pA][0], g1 = mwgt[pA][1], g2 = mwgt[pA][2], g3 = mwgt[pA][3];
        const size_t cbase = (size_t)(b * 256 + ch * 64 + cgA * 16) * 4096;
        float* Sp = &S[(cgA * 16) * 64 + pA];
#pragma unroll 4
        for (int j = 0; j < 16; j++) {
          const size_t xo = cbase + (size_t)j * 4096;
          float v = g0 * ldi(x, xo + i0, f) + g1 * ldi(x, xo + i1, f)
                  + g2 * ldi(x, xo + i2, f) + g3 * ldi(x, xo + i3, f);
          Sp[j * 64] = v;
        }
      }
      __syncthreads();
      const float* wk = wdcnT + (size_t)k * 32768 + (size_t)(ch * 64) * 128;
#pragma unroll 2
      for (int c2 = 0; c2 < 64; c2++) {
        float4 a0 = *(const float4*)&wk[c2 * 128 + og * 8];
        float4 a1 = *(const float4*)&wk[c2 * 128 + og * 8 + 4];
        float4 s4 = *(const float4*)&S[c2 * 64 + pg * 4];
        float aa[8] = {a0.x, a0.y, a0.z, a0.w, a1.x, a1.y, a1.z, a1.w};
        float ss[4] = {s4.x, s4.y, s4.z, s4.w};
#pragma unroll
        for (int j = 0; j < 8; j++)
#pragma unroll
          for (int i = 0; i < 4; i++)
            acc[j][i] = fmaf(aa[j], ss[i], acc[j][i]);
      }
    }
  }
#pragma unroll
  for (int j = 0; j < 8; j++) {
    const int o = og * 8 + j;
    float bd = ldi(b_dcn, o, f);
    float v0 = acc[j][0] + bd, v1 = acc[j][1] + bd, v2 = acc[j][2] + bd, v3 = acc[j][3] + bd;
    float s = v0 + v1 + v2 + v3;
    float q = v0 * v0 + v1 * v1 + v2 * v2 + v3 * v3;
    uint2 pkv = make_uint2(pk2(v0, v1), pk2(v2, v3));
    *(uint2*)(h1 + (size_t)((b * 128 + o) * 64 + h) * 64 + pg * 4) = pkv;
#pragma unroll
    for (int m = 1; m < 16; m <<= 1) {
      s += __shfl_xor(s, m, 64);
      q += __shfl_xor(q, m, 64);
    }
    if (pg == 0) { atomicAdd(&g_stats[o], s); atomicAdd(&g_stats[128 + o], q); }
  }
}

// ---------- K3: BN1 + ReLU in place on h1 ----------
__global__ void k_bn1(unsigned short* __restrict__ h1, const void* __restrict__ g1,
                      const void* __restrict__ be1) {
  const int f = g_isf32;
  int gid = blockIdx.x * 256 + threadIdx.x;
  size_t base = (size_t)gid * 8;
  int o = (int)((base >> 12) & 127);
  float mu = g_stats[o] * (1.f / 32768.f);
  float var = g_stats[128 + o] * (1.f / 32768.f) - mu * mu;
  float sc = rsqrtf(var + 1e-5f) * ldi(g1, o, f);
  float sh = ldi(be1, o, f) - mu * sc;
  uint4 p = *(const uint4*)(h1 + base);
  unsigned int pp[4] = {p.x, p.y, p.z, p.w};
  unsigned int r[4];
#pragma unroll
  for (int i = 0; i < 4; i++) {
    float f0 = fmaxf(fmaf(bf2f((unsigned short)(pp[i] & 0xffff)), sc, sh), 0.f);
    float f1 = fmaxf(fmaf(bf2f((unsigned short)(pp[i] >> 16)), sc, sh), 0.f);
    r[i] = pk2(f0, f1);
  }
  *(uint4*)(h1 + base) = make_uint4(r[0], r[1], r[2], r[3]);
}

// ---------- K4 (fast): parity-decomposed transposed conv as MFMA GEMM ----------
// grid (nt=32, par=4, b=8).  C[128m x 128n] : n = 2 y'-rows x 64 x'.
__global__ __launch_bounds__(256) void k_ctgemm(
    const unsigned short* __restrict__ h1n, const unsigned short* __restrict__ Apar,
    void* __restrict__ out2) {
  const int f = g_isf32;
  const int nt = blockIdx.x, par = blockIdx.y, b = blockIdx.z;
  const int py = par >> 1, px = par & 1;
  const int t = threadIdx.x;
  const int wv = t >> 6, L = t & 63;
  const int quad = L >> 4, l15 = L & 15;
  const int wm = (wv >> 1) * 64, wn = (wv & 1) * 64;
  __shared__ unsigned short As[128][40];
  __shared__ unsigned short Bs[128][40];
  f32x4 acc[4][4] = {};
  const int y0 = nt * 2;
  const unsigned short* Ap = Apar + (size_t)par * 128 * 512;
  const unsigned short* hb = h1n + (size_t)b * 128 * 4096;

  for (int kk = 0; kk < 512; kk += 32) {
    const int tap = kk >> 7, ic = kk & 127;
    const int a = tap >> 1, bb = tap & 1;
    const int ya = (py == 0) ? (a ? -1 : 0) : (a ? 0 : 1);
    const int xb = (px == 0) ? (bb ? -1 : 0) : (bb ? 0 : 1);
    __syncthreads();
    {   // A-tile 128x32
      int m = t >> 1, seg = t & 1;
      const unsigned short* ap = Ap + (size_t)m * 512 + kk + seg * 16;
      uint4 q0 = *(const uint4*)(ap);
      uint4 q1 = *(const uint4*)(ap + 8);
      *(uint4*)&As[m][seg * 16]     = q0;
      *(uint4*)&As[m][seg * 16 + 8] = q1;
    }
    {   // B-tile: 32 channels of this tap, parity-shifted h1 view, zero-padded
      int kr = t & 31, oct = t >> 5;
      int rr = oct >> 2, xq = (oct & 3) * 16;
      int srcy = y0 + rr + ya;
      const unsigned short* hp = hb + (size_t)(ic + kr) * 4096 + srcy * 64;
      bool yok = (srcy >= 0) && (srcy < 64);
      unsigned short* bsp = &Bs[oct * 16][kr];
#pragma unroll
      for (int j = 0; j < 16; j++) {
        int srcx = xq + j + xb;
        unsigned short v = 0;
        if (yok && srcx >= 0 && srcx < 64) v = hp[srcx];
        bsp[j * 40] = v;
      }
    }
    __syncthreads();
    const int ar = quad * 8;
    bf16x8 af[4], bfr[4];
#pragma unroll
    for (int tm = 0; tm < 4; tm++) af[tm]  = *(const bf16x8*)&As[wm + tm * 16 + l15][ar];
#pragma unroll
    for (int tn = 0; tn < 4; tn++) bfr[tn] = *(const bf16x8*)&Bs[wn + tn * 16 + l15][ar];
#pragma unroll
    for (int tm = 0; tm < 4; tm++)
#pragma unroll
      for (int tn = 0; tn < 4; tn++)
        acc[tm][tn] = __builtin_amdgcn_mfma_f32_16x16x32_bf16(af[tm], bfr[tn], acc[tm][tn], 0, 0, 0);
  }

#pragma unroll
  for (int tm = 0; tm < 4; tm++) {
#pragma unroll
    for (int r = 0; r < 4; r++) {
      int m = wm + tm * 16 + quad * 4 + r;
      float s = 0.f, q = 0.f;
#pragma unroll
      for (int tn = 0; tn < 4; tn++) {
        float v = acc[tm][tn][r];
        int n = wn + tn * 16 + l15;
        int yy = 2 * (y0 + (n >> 6)) + py;
        int xx = 2 * (n & 63) + px;
        size_t ofs = (size_t)((b * 128 + m) * 128 + yy) * 128 + xx;
        if (f) ((float*)out2)[ofs] = v;
        else   ((unsigned short*)out2)[ofs] = f2bf(v);
        s += v; q += v * v;
      }
#pragma unroll
      for (int msk2 = 1; msk2 < 16; msk2 <<= 1) {
        s += __shfl_xor(s, msk2, 64);
        q += __shfl_xor(q, msk2, 64);
      }
      if (l15 == 0) { atomicAdd(&g_stats[256 + m], s); atomicAdd(&g_stats[384 + m], q); }
    }
  }
}

// ---------- K4 fallback: fp32 VALU transposed conv ----------
__global__ __launch_bounds__(256) void k_ctconv(
    const unsigned short* __restrict__ h1n, const float* __restrict__ wctT,
    void* __restrict__ out2) {
  const int f = g_isf32;
  const int y = blockIdx.x, b = blockIdx.y;
  const int t = threadIdx.x;
  const int og = t >> 3, xg = t & 7;
  __shared__ float hs[2 * 32 * 68];
  int kr0, kr1, r0, r1;
  if ((y & 1) == 0) { kr0 = 1; r0 = y >> 1; kr1 = 3; r1 = (y >> 1) - 1; }
  else              { kr0 = 0; r0 = (y + 1) >> 1; kr1 = 2; r1 = (y - 1) >> 1; }
  float acc[4][16];
#pragma unroll
  for (int j = 0; j < 4; j++)
#pragma unroll
    for (int i = 0; i < 16; i++) acc[j][i] = 0.f;

  for (int ihc = 0; ihc < 4; ihc++) {
    __syncthreads();
    for (int e = t; e < 2 * 32 * 64; e += 256) {
      int rr = e >> 11, rem = e & 2047, il = rem >> 6, w = rem & 63;
      int i = ihc * 32 + il;
      int row = rr ? r1 : r0;
      float v = 0.f;
      if (row >= 0 && row < 64)
        v = bf2f(h1n[(size_t)((b * 128 + i) * 64 + row) * 64 + w]);
      hs[(rr * 32 + il) * 68 + w + 1] = v;
    }
    for (int e = t; e < 64; e += 256) {
      int base = e * 68;
      hs[base] = 0.f; hs[base + 65] = 0.f; hs[base + 66] = 0.f; hs[base + 67] = 0.f;
    }
    __syncthreads();
    for (int il = 0; il < 32; il++) {
      const int i = ihc * 32 + il;
      float br[2][12];
#pragma unroll
      for (int rr = 0; rr < 2; rr++) {
        const float* p = &hs[(rr * 32 + il) * 68 + xg * 8];
        float4 q0 = *(const float4*)(p);
        float4 q1 = *(const float4*)(p + 4);
        float4 q2 = *(const float4*)(p + 8);
        br[rr][0] = q0.x; br[rr][1] = q0.y; br[rr][2] = q0.z; br[rr][3] = q0.w;
        br[rr][4] = q1.x; br[rr][5] = q1.y; br[rr][6] = q1.z; br[rr][7] = q1.w;
        br[rr][8] = q2.x; br[rr][9] = q2.y; br[rr][10] = q2.z; br[rr][11] = q2.w;
      }
      float a[2][4][4];
#pragma unroll
      for (int rr = 0; rr < 2; rr++) {
        const int krr = rr ? kr1 : kr0;
#pragma unroll
        for (int kc = 0; kc < 4; kc++) {
          float4 av = *(const float4*)&wctT[((size_t)(krr * 4 + kc) * 128 + i) * 128 + og * 4];
          a[rr][kc][0] = av.x; a[rr][kc][1] = av.y; a[rr][kc][2] = av.z; a[rr][kc][3] = av.w;
        }
      }
#pragma unroll
      for (int xi = 0; xi < 16; xi++) {
        const int u = xi >> 1;
        const int kcA = (xi & 1) ? 0 : 1;
        const int lwA = (xi & 1) ? u + 2 : u + 1;
        const int kcB = (xi & 1) ? 2 : 3;
        const int lwB = (xi & 1) ? u + 1 : u;
#pragma unroll
        for (int rr = 0; rr < 2; rr++) {
#pragma unroll
          for (int j = 0; j < 4; j++) {
            acc[j][xi] = fmaf(a[rr][kcA][j], br[rr][lwA], acc[j][xi]);
            acc[j][xi] = fmaf(a[rr][kcB][j], br[rr][lwB], acc[j][xi]);
          }
        }
      }
    }
  }
#pragma unroll
  for (int j = 0; j < 4; j++) {
    const int o = og * 4 + j;
    float s = 0.f, q = 0.f;
#pragma unroll
    for (int xi = 0; xi < 16; xi++) { s += acc[j][xi]; q += acc[j][xi] * acc[j][xi]; }
    size_t ofs = (size_t)((b * 128 + o) * 128 + y) * 128 + xg * 16;
    if (f) {
      float* op = (float*)out2 + ofs;
#pragma unroll
      for (int v4 = 0; v4 < 4; v4++)
        ((float4*)op)[v4] = make_float4(acc[j][4 * v4], acc[j][4 * v4 + 1],
                                        acc[j][4 * v4 + 2], acc[j][4 * v4 + 3]);
    } else {
      unsigned int w_[8];
#pragma unroll
      for (int xi = 0; xi < 8; xi++) w_[xi] = pk2(acc[j][2 * xi], acc[j][2 * xi + 1]);
      unsigned short* op = (unsigned short*)out2 + ofs;
      *(uint4*)(op)     = make_uint4(w_[0], w_[1], w_[2], w_[3]);
      *(uint4*)(op + 8) = make_uint4(w_[4], w_[5], w_[6], w_[7]);
    }
#pragma unroll
    for (int m = 1; m < 8; m <<= 1) {
      s += __shfl_xor(s, m, 64);
      q += __shfl_xor(q, m, 64);
    }
    if (xg == 0) { atomicAdd(&g_stats[256 + o], s); atomicAdd(&g_stats[384 + o], q); }
  }
}

// ---------- K5: BN2 + ReLU in place on d_out ----------
__global__ void k_bn2(void* __restrict__ out2, const void* __restrict__ g2,
                      const void* __restrict__ be2) {
  const int f = g_isf32;
  int gid = blockIdx.x * 256 + threadIdx.x;
  size_t base = (size_t)gid * 8;
  int o = (int)((base >> 14) & 127);
  float mu = g_stats[256 + o] * (1.f / 131072.f);
  float var = g_stats[384 + o] * (1.f / 131072.f) - mu * mu;
  float sc = rsqrtf(var + 1e-5f) * ldi(g2, o, f);
  float sh = ldi(be2, o, f) - mu * sc;
  if (f) {
    float4* op = (float4*)out2 + gid * 2;
    float4 p0 = op[0], p1 = op[1];
    p0.x = fmaxf(fmaf(p0.x, sc, sh), 0.f); p0.y = fmaxf(fmaf(p0.y, sc, sh), 0.f);
    p0.z = fmaxf(fmaf(p0.z, sc, sh), 0.f); p0.w = fmaxf(fmaf(p0.w, sc, sh), 0.f);
    p1.x = fmaxf(fmaf(p1.x, sc, sh), 0.f); p1.y = fmaxf(fmaf(p1.y, sc, sh), 0.f);
    p1.z = fmaxf(fmaf(p1.z, sc, sh), 0.f); p1.w = fmaxf(fmaf(p1.w, sc, sh), 0.f);
    op[0] = p0; op[1] = p1;
  } else {
    unsigned short* ob = (unsigned short*)out2 + base;
    uint4 p = *(const uint4*)ob;
    unsigned int pp[4] = {p.x, p.y, p.z, p.w};
    unsigned int r[4];
#pragma unroll
    for (int i = 0; i < 4; i++) {
      float f0 = fmaxf(fmaf(bf2f((unsigned short)(pp[i] & 0xffff)), sc, sh), 0.f);
      float f1 = fmaxf(fmaf(bf2f((unsigned short)(pp[i] >> 16)), sc, sh), 0.f);
      r[i] = pk2(f0, f1);
    }
    *(uint4*)ob = make_uint4(r[0], r[1], r[2], r[3]);
  }
}

// ---------- launch ----------
extern "C" void kernel_launch(void* const* d_in, const int* in_sizes, int n_in,
                              void* d_out, int out_size, void* d_ws, size_t ws_size,
                              hipStream_t stream) {
  const void* x     = d_in[0];
  const void* w_off = d_in[1];
  const void* b_off = d_in[2];
  const void* w_dcn = d_in[3];
  const void* b_dcn = d_in[4];
  const void* g1    = d_in[5];
  const void* be1   = d_in[6];
  const void* w_ct  = d_in[7];
  const void* g2    = d_in[8];
  const void* be2   = d_in[9];

  char* ws = (char*)d_ws;
  const bool fast = ws_size >= (size_t)166000000;

  unsigned short* Sbuf; unsigned short* h1; float* om; float* wdcnT; float* wctT;
  float* woffT; unsigned short* wdcnA; unsigned short* AparB;
  if (fast) {
    Sbuf  = (unsigned short*)(ws + 0);            // 150,994,944 B
    h1    = (unsigned short*)(ws + 150994944);    //   8,388,608 B
    om    = (float*)(ws + 159383552);             //   3,538,944 B
    wdcnT = (float*)(ws + 162922496);             //   1,179,648 B (dead in fast path)
    wctT  = (float*)(ws + 164102144);             //   1,048,576 B
    woffT = (float*)(ws + 165150720);             //     248,832 B
    wdcnA = (unsigned short*)(ws + 165399552);    //     589,824 B -> 165,989,376
    AparB = (unsigned short*)(ws + 162922496);    // 524,288 B, aliases wdcnT
  } else {
    Sbuf  = nullptr;
    h1    = (unsigned short*)(ws + 0);
    om    = (float*)(ws + 8388608);
    wdcnT = (float*)(ws + 11927552);
    wctT  = (float*)(ws + 13107200);
    woffT = (float*)(ws + 14155776);
    wdcnA = (unsigned short*)(ws + 14404608);
    AparB = nullptr;
  }

  k_detect<<<dim3(1), 256, 0, stream>>>((const unsigned short*)x);
  k_prep<<<dim3(3571), 256, 0, stream>>>(w_dcn, w_ct, w_off, wdcnT, wctT, woffT, wdcnA);
  k_offconv<<<dim3(64, 8), 256, 0, stream>>>(x, b_off, woffT, om);
  if (fast) {
    k_prep2<<<dim3(1024), 256, 0, stream>>>(wctT, AparB);
    k_sample<<<dim3(64, 8, 4), 256, 0, stream>>>(x, om, Sbuf);
    k_gemm_dcn<<<dim3(32, 8), 256, 0, stream>>>(wdcnA, Sbuf, b_dcn, h1);
    k_bn1<<<dim3(2048), 256, 0, stream>>>(h1, g1, be1);
    k_ctgemm<<<dim3(32, 4, 8), 256, 0, stream>>>(h1, AparB, d_out);
  } else {
    k_dcn<<<dim3(64, 8), 256, 0, stream>>>(x, om, wdcnT, b_dcn, h1);
    k_bn1<<<dim3(2048), 256, 0, stream>>>(h1, g1, be1);
    k_ctconv<<<dim3(128, 8), 256, 0, stream>>>(h1, wctT, d_out);
  }
  k_bn2<<<dim3(8192), 256, 0, stream>>>(d_out, g2, be2);
}

// Round 7
// 872.308 us; speedup vs baseline: 1.4855x; 1.0888x over previous
//
#include <hip/hip_runtime.h>
#include <stdint.h>

// ---------- device globals: dtype flag + BN stats ----------
__device__ int   g_isf32;
__device__ float g_stats[512];  // [0:128) s1sum, [128:256) s1sq, [256:384) s2sum, [384:512) s2sq

typedef __attribute__((ext_vector_type(8))) short bf16x8;
typedef __attribute__((ext_vector_type(4))) float f32x4;

// ---------- bf16 helpers ----------
__device__ __forceinline__ float bf2f(unsigned short u) {
  union { unsigned int i; float f; } v; v.i = ((unsigned int)u) << 16; return v.f;
}
__device__ __forceinline__ unsigned short f2bf(float f) {
  union { float f; unsigned int i; } v; v.f = f;
  unsigned int r = v.i + 0x7FFFu + ((v.i >> 16) & 1u);
  return (unsigned short)(r >> 16);
}
__device__ __forceinline__ unsigned int pk2(float a, float b) {
  return (unsigned int)f2bf(a) | ((unsigned int)f2bf(b) << 16);
}
// dtype-flex input load: f ? fp32 : bf16
__device__ __forceinline__ float ldi(const void* p, size_t i, int f) {
  return f ? ((const float*)p)[i] : bf2f(((const unsigned short*)p)[i]);
}

// ---------- K0: dtype detector + stats zeroing ----------
__global__ void k_detect(const unsigned short* __restrict__ x) {
  __shared__ int cnt;
  const int t = threadIdx.x;
  if (t == 0) cnt = 0;
  g_stats[t] = 0.f; g_stats[t + 256] = 0.f;
  __syncthreads();
  int c = 0;
  for (int j = 0; j < 16; j++) {
    unsigned short u = x[t * 16 + j];
    int e = (u >> 7) & 0xFF;
    if (e == 0xFF || (e != 0 && e <= 100)) c++;
  }
  atomicAdd(&cnt, c);
  __syncthreads();
  if (t == 0) g_isf32 = (cnt > 256) ? 1 : 0;
}

// ---------- K_prep: weights -> GEMM-friendly layouts ----------
__global__ void k_prep(const void* __restrict__ w_dcn, const void* __restrict__ w_ct,
                       const void* __restrict__ w_off,
                       float* __restrict__ wdcnT, float* __restrict__ wctT,
                       float* __restrict__ woffT, unsigned short* __restrict__ wdcnA) {
  const int f = g_isf32;
  int idx = blockIdx.x * 256 + threadIdx.x;
  if (idx < 294912) {
    int k = idx / 32768, c = (idx >> 7) & 255, o = idx & 127;
    wdcnT[idx] = ldi(w_dcn, (size_t)(o * 256 + c) * 9 + k, f);
  }
  int i2 = idx - 294912;
  if (i2 >= 0 && i2 < 262144) {
    int kr = i2 >> 16, kc = (i2 >> 14) & 3, i = (i2 >> 7) & 127, o = i2 & 127;
    wctT[i2] = ldi(w_ct, (size_t)((i * 128 + o) * 4 + kr) * 4 + kc, f);
  }
  int i3 = idx - (294912 + 262144);
  if (i3 >= 0 && i3 < 62208) {
    int ci = i3 / 243, r = i3 - ci * 243, k = r / 27, c = r - (r / 27) * 27;
    woffT[i3] = ldi(w_off, (size_t)(c * 256 + ci) * 9 + k, f);
  }
  int i4 = idx - 619264;
  if (i4 >= 0 && i4 < 294912) {
    int o = i4 / 2304, rem = i4 - o * 2304;
    int k = rem >> 8, c = rem & 255;
    wdcnA[i4] = f2bf(ldi(w_dcn, (size_t)(o * 256 + c) * 9 + k, f));
  }
}

// ---------- K_prep2: parity-decomposed ct-conv A matrices (fast path only) ----------
// Apar[par][o][tap*128 + i] bf16, par = py*2+px, tap = a*2+b
__global__ void k_prep2(const float* __restrict__ wctT, unsigned short* __restrict__ Apar) {
  int idx = blockIdx.x * 256 + threadIdx.x;   // 262144
  int par = idx >> 16, rem = idx & 65535;
  int o = rem >> 9, rem2 = rem & 511;
  int tap = rem2 >> 7, i = rem2 & 127;
  int py = par >> 1, px = par & 1, a = tap >> 1, bb = tap & 1;
  int kr = (py == 0) ? (a ? 3 : 1) : (a ? 2 : 0);
  int kc = (px == 0) ? (bb ? 3 : 1) : (bb ? 2 : 0);
  Apar[idx] = f2bf(wctT[((size_t)(kr * 4 + kc) * 128 + i) * 128 + o]);
}

// ---------- K1: 3x3 offset conv, pad 1.  om (8,27,64,64) fp32 ----------
__global__ __launch_bounds__(256) void k_offconv(
    const void* __restrict__ x, const void* __restrict__ b_off,
    const float* __restrict__ woffT, float* __restrict__ om) {
  const int f = g_isf32;
  const int h = blockIdx.x, b = blockIdx.y;
  const int t = threadIdx.x;
  const int cg = t & 31, wg = t >> 5;
  const int w0 = wg * 8;
  __shared__ float xs[32 * 204];
  float acc[8];
#pragma unroll
  for (int i = 0; i < 8; i++) acc[i] = 0.f;

  for (int cb = 0; cb < 256; cb += 32) {
    __syncthreads();
    for (int e = t; e < 32 * 192; e += 256) {
      int ci = e / 192, r = e - ci * 192;
      int dh = r >> 6, w = r & 63;
      int row = h + dh - 1;
      float v = 0.f;
      if (row >= 0 && row < 64)
        v = ldi(x, ((size_t)((b * 256 + cb + ci) * 64 + row) << 6) + w, f);
      xs[ci * 204 + dh * 68 + w + 1] = v;
    }
    for (int e = t; e < 96; e += 256) {
      int base = (e / 3) * 204 + (e - (e / 3) * 3) * 68;
      xs[base] = 0.f; xs[base + 65] = 0.f; xs[base + 66] = 0.f; xs[base + 67] = 0.f;
    }
    __syncthreads();

    for (int ci = 0; ci < 32; ci++) {
      float xr[3][12];
#pragma unroll
      for (int dh = 0; dh < 3; dh++) {
        const float* p = &xs[ci * 204 + dh * 68 + w0];
        float4 q0 = *(const float4*)(p);
        float4 q1 = *(const float4*)(p + 4);
        float4 q2 = *(const float4*)(p + 8);
        xr[dh][0] = q0.x; xr[dh][1] = q0.y; xr[dh][2] = q0.z; xr[dh][3] = q0.w;
        xr[dh][4] = q1.x; xr[dh][5] = q1.y; xr[dh][6] = q1.z; xr[dh][7] = q1.w;
        xr[dh][8] = q2.x; xr[dh][9] = q2.y; xr[dh][10] = q2.z; xr[dh][11] = q2.w;
      }
      if (cg < 27) {
        const float* wp = &woffT[(size_t)(cb + ci) * 243 + cg];
#pragma unroll
        for (int k = 0; k < 9; k++) {
          float wk = wp[k * 27];
          const int dh = k / 3, dx = k - (k / 3) * 3;
#pragma unroll
          for (int wi = 0; wi < 8; wi++)
            acc[wi] = fmaf(wk, xr[dh][wi + dx], acc[wi]);
        }
      }
    }
  }
  if (cg < 27) {
    float bo = ldi(b_off, cg, f);
    float* op = &om[(size_t)((b * 27 + cg) * 64 + h) * 64 + w0];
#pragma unroll
    for (int wi = 0; wi < 8; wi++) op[wi] = acc[wi] + bo;
  }
}

// ---------- K2a: deformable bilinear sampling -> S[b][k*256+c][h*64+w] bf16 ----------
__global__ __launch_bounds__(256) void k_sample(
    const void* __restrict__ x, const float* __restrict__ om,
    unsigned short* __restrict__ S) {
  const int f = g_isf32;
  const int h = blockIdx.x, b = blockIdx.y, cq = blockIdx.z;
  const int t = threadIdx.x;
  const int w = t & 63, wv = t >> 6;
  const int c0 = cq * 64;
  const float* ob = om + (size_t)(b * 27) * 4096 + h * 64 + w;
  for (int k = 0; k < 9; k++) {
    float oy = ob[(size_t)k * 4096];
    float ox = ob[(size_t)(k + 9) * 4096];
    float mm = ob[(size_t)(k + 18) * 4096];
    float msk = 1.f / (1.f + expf(-mm));
    float py = oy + (float)(h - 1 + k / 3);
    float px = ox + (float)(w - 1 + (k - (k / 3) * 3));
    float y0f = floorf(py), x0f = floorf(px);
    float ly = py - y0f, lx = px - x0f;
    int y0 = (int)y0f, x0 = (int)x0f;
    int y1 = y0 + 1, x1 = x0 + 1;
    float fy0 = (y0 >= 0 && y0 < 64) ? 1.f : 0.f;
    float fy1 = (y1 >= 0 && y1 < 64) ? 1.f : 0.f;
    float fx0 = (x0 >= 0 && x0 < 64) ? 1.f : 0.f;
    float fx1 = (x1 >= 0 && x1 < 64) ? 1.f : 0.f;
    int y0c = min(max(y0, 0), 63), y1c = min(max(y1, 0), 63);
    int x0c = min(max(x0, 0), 63), x1c = min(max(x1, 0), 63);
    int i0 = y0c * 64 + x0c, i1 = y0c * 64 + x1c;
    int i2 = y1c * 64 + x0c, i3 = y1c * 64 + x1c;
    float g0 = (1.f - ly) * (1.f - lx) * msk * fy0 * fx0;
    float g1 = (1.f - ly) * lx * msk * fy0 * fx1;
    float g2 = ly * (1.f - lx) * msk * fy1 * fx0;
    float g3 = ly * lx * msk * fy1 * fx1;
    unsigned short* Sp = S + ((size_t)(b * 9 + k) * 256) * 4096 + h * 64 + w;
    const size_t xb0 = (size_t)b * 256 * 4096;
#pragma unroll 4
    for (int c = c0 + wv; c < c0 + 64; c += 4) {
      size_t xo = xb0 + (size_t)c * 4096;
      float v = g0 * ldi(x, xo + i0, f) + g1 * ldi(x, xo + i1, f)
              + g2 * ldi(x, xo + i2, f) + g3 * ldi(x, xo + i3, f);
      Sp[(size_t)c * 4096] = f2bf(v);
    }
  }
}

// ---------- K2b: MFMA GEMM  h1[b](128,4096) = wdcnA(128,2304) x S[b](2304,4096) ----------
__global__ __launch_bounds__(256) void k_gemm_dcn(
    const unsigned short* __restrict__ A,   // [128][2304] bf16
    const unsigned short* __restrict__ S,   // [8][2304][4096] bf16
    const void* __restrict__ b_dcn,
    unsigned short* __restrict__ h1) {
  const int f = g_isf32;
  const int nt = blockIdx.x;   // 0..31
  const int b  = blockIdx.y;
  const int t  = threadIdx.x;
  const int wv = t >> 6, L = t & 63;
  const int quad = L >> 4, l15 = L & 15;
  const int wm = (wv >> 1) * 64, wn = (wv & 1) * 64;
  __shared__ unsigned short As[128][40];
  __shared__ unsigned short Bs[128][40];
  f32x4 acc[4][4] = {};
  const unsigned short* Sb = S + (size_t)b * 2304 * 4096 + (size_t)nt * 128;

  for (int kk = 0; kk < 2304; kk += 32) {
    __syncthreads();
    {   // stage A-tile 128x32
      int m = t >> 1, seg = t & 1;
      const unsigned short* ap = A + (size_t)m * 2304 + kk + seg * 16;
      uint4 q0 = *(const uint4*)(ap);
      uint4 q1 = *(const uint4*)(ap + 8);
      *(uint4*)&As[m][seg * 16]     = q0;
      *(uint4*)&As[m][seg * 16 + 8] = q1;
    }
    {   // stage B-tile 32x128 transposed; kr fast in lane -> <=2-way LDS conflicts
      int kr = t & 31, oct = t >> 5;
      const unsigned short* bp = Sb + (size_t)(kk + kr) * 4096 + oct * 16;
      uint4 q0 = *(const uint4*)(bp);
      uint4 q1 = *(const uint4*)(bp + 8);
      unsigned short e[16];
      *(uint4*)&e[0] = q0; *(uint4*)&e[8] = q1;
#pragma unroll
      for (int j = 0; j < 16; j++) Bs[oct * 16 + j][kr] = e[j];
    }
    __syncthreads();
    const int ar = quad * 8;
    bf16x8 af[4], bfr[4];
#pragma unroll
    for (int tm = 0; tm < 4; tm++) af[tm]  = *(const bf16x8*)&As[wm + tm * 16 + l15][ar];
#pragma unroll
    for (int tn = 0; tn < 4; tn++) bfr[tn] = *(const bf16x8*)&Bs[wn + tn * 16 + l15][ar];
#pragma unroll
    for (int tm = 0; tm < 4; tm++)
#pragma unroll
      for (int tn = 0; tn < 4; tn++)
        acc[tm][tn] = __builtin_amdgcn_mfma_f32_16x16x32_bf16(af[tm], bfr[tn], acc[tm][tn], 0, 0, 0);
  }

#pragma unroll
  for (int tm = 0; tm < 4; tm++) {
#pragma unroll
    for (int r = 0; r < 4; r++) {
      int m = wm + tm * 16 + quad * 4 + r;
      float bd = ldi(b_dcn, m, f);
      float s = 0.f, q = 0.f;
#pragma unroll
      for (int tn = 0; tn < 4; tn++) {
        float v = acc[tm][tn][r] + bd;
        int n = nt * 128 + wn + tn * 16 + l15;
        h1[(size_t)(b * 128 + m) * 4096 + n] = f2bf(v);
        s += v; q += v * v;
      }
#pragma unroll
      for (int msk = 1; msk < 16; msk <<= 1) {
        s += __shfl_xor(s, msk, 64);
        q += __shfl_xor(q, msk, 64);
      }
      if (l15 == 0) { atomicAdd(&g_stats[m], s); atomicAdd(&g_stats[128 + m], q); }
    }
  }
}

// ---------- K2 fallback: fused sampling + fp32 GEMM ----------
__global__ __launch_bounds__(256) void k_dcn(
    const void* __restrict__ x, const float* __restrict__ om,
    const float* __restrict__ wdcnT, const void* __restrict__ b_dcn,
    unsigned short* __restrict__ h1) {
  const int f = g_isf32;
  const int h = blockIdx.x, b = blockIdx.y;
  const int t = threadIdx.x;
  __shared__ float S[64 * 64];
  __shared__ int   midx[64][4];
  __shared__ float mwgt[64][4];
  const int og = t >> 4, pg = t & 15;
  const int pA = t & 63, cgA = t >> 6;
  float acc[8][4];
#pragma unroll
  for (int j = 0; j < 8; j++)
#pragma unroll
    for (int i = 0; i < 4; i++) acc[j][i] = 0.f;

  for (int k = 0; k < 9; k++) {
    if (t < 64) {
      const int w = t;
      const float* ob = &om[(size_t)(b * 27) * 4096 + h * 64 + w];
      float oy = ob[(size_t)k * 4096];
      float ox = ob[(size_t)(k + 9) * 4096];
      float mm = ob[(size_t)(k + 18) * 4096];
      float msk = 1.f / (1.f + expf(-mm));
      float py = oy + (float)(h - 1 + k / 3);
      float px = ox + (float)(w - 1 + (k - (k / 3) * 3));
      float y0f = floorf(py), x0f = floorf(px);
      float ly = py - y0f, lx = px - x0f;
      int y0 = (int)y0f, x0 = (int)x0f;
      int y1 = y0 + 1, x1 = x0 + 1;
      float fy0 = (y0 >= 0 && y0 < 64) ? 1.f : 0.f;
      float fy1 = (y1 >= 0 && y1 < 64) ? 1.f : 0.f;
      float fx0 = (x0 >= 0 && x0 < 64) ? 1.f : 0.f;
      float fx1 = (x1 >= 0 && x1 < 64) ? 1.f : 0.f;
      int y0c = min(max(y0, 0), 63), y1c = min(max(y1, 0), 63);
      int x0c = min(max(x0, 0), 63), x1c = min(max(x1, 0), 63);
      midx[w][0] = y0c * 64 + x0c;
      midx[w][1] = y0c * 64 + x1c;
      midx[w][2] = y1c * 64 + x0c;
      midx[w][3] = y1c * 64 + x1c;
      mwgt[w][0] = (1.f - ly) * (1.f - lx) * msk * fy0 * fx0;
      mwgt[w][1] = (1.f - ly) * lx * msk * fy0 * fx1;
      mwgt[w][2] = ly * (1.f - lx) * msk * fy1 * fx0;
      mwgt[w][3] = ly * lx * msk * fy1 * fx1;
    }
    for (int ch = 0; ch < 4; ch++) {
      __syncthreads();
      {
        const int i0 = midx[pA][0], i1 = midx[pA][1], i2 = midx[pA][2], i3 = midx[pA][3];
        const float g0 = mwgt[pA][0], g1 = mwgt[pA][1], g2 = mwgt[pA][2], g3 = mwgt[pA][3];
        const size_t cbase = (size_t)(b * 256 + ch * 64 + cgA * 16) * 4096;
        float* Sp = &S[(cgA * 16) * 64 + pA];
#pragma unroll 4
        for (int j = 0; j < 16; j++) {
          const size_t xo = cbase + (size_t)j * 4096;
          float v = g0 * ldi(x, xo + i0, f) + g1 * ldi(x, xo + i1, f)
                  + g2 * ldi(x, xo + i2, f) + g3 * ldi(x, xo + i3, f);
          Sp[j * 64] = v;
        }
      }
      __syncthreads();
      const float* wk = wdcnT + (size_t)k * 32768 + (size_t)(ch * 64) * 128;
#pragma unroll 2
      for (int c2 = 0; c2 < 64; c2++) {
        float4 a0 = *(const float4*)&wk[c2 * 128 + og * 8];
        float4 a1 = *(const float4*)&wk[c2 * 128 + og * 8 + 4];
        float4 s4 = *(const float4*)&S[c2 * 64 + pg * 4];
        float aa[8] = {a0.x, a0.y, a0.z, a0.w, a1.x, a1.y, a1.z, a1.w};
        float ss[4] = {s4.x, s4.y, s4.z, s4.w};
#pragma unroll
        for (int j = 0; j < 8; j++)
#pragma unroll
          for (int i = 0; i < 4; i++)
            acc[j][i] = fmaf(aa[j], ss[i], acc[j][i]);
      }
    }
  }
#pragma unroll
  for (int j = 0; j < 8; j++) {
    const int o = og * 8 + j;
    float bd = ldi(b_dcn, o, f);
    float v0 = acc[j][0] + bd, v1 = acc[j][1] + bd, v2 = acc[j][2] + bd, v3 = acc[j][3] + bd;
    float s = v0 + v1 + v2 + v3;
    float q = v0 * v0 + v1 * v1 + v2 * v2 + v3 * v3;
    uint2 pkv = make_uint2(pk2(v0, v1), pk2(v2, v3));
    *(uint2*)(h1 + (size_t)((b * 128 + o) * 64 + h) * 64 + pg * 4) = pkv;
#pragma unroll
    for (int m = 1; m < 16; m <<= 1) {
      s += __shfl_xor(s, m, 64);
      q += __shfl_xor(q, m, 64);
    }
    if (pg == 0) { atomicAdd(&g_stats[o], s); atomicAdd(&g_stats[128 + o], q); }
  }
}

// ---------- K3 (fast): BN1 + ReLU + transpose  h1[b][ch][pos] -> h1T[b][pos][ch] ----------
// grid (64 pos-tiles, 2 ch-halves, 8 b); 64x64 LDS tile.
__global__ __launch_bounds__(256) void k_bn1t(
    const unsigned short* __restrict__ h1, const void* __restrict__ g1,
    const void* __restrict__ be1, unsigned short* __restrict__ h1T) {
  const int f = g_isf32;
  const int pt = blockIdx.x, chh = blockIdx.y, b = blockIdx.z;
  const int t = threadIdx.x;
  __shared__ unsigned short T[64][72];
  const int c0 = chh * 64, p0 = pt * 64;
  {
    int cl = t >> 2, q = t & 3;
    int o = c0 + cl;
    float mu = g_stats[o] * (1.f / 32768.f);
    float var = g_stats[128 + o] * (1.f / 32768.f) - mu * mu;
    float sc = rsqrtf(var + 1e-5f) * ldi(g1, o, f);
    float sh = ldi(be1, o, f) - mu * sc;
    const unsigned short* hp = h1 + (size_t)(b * 128 + o) * 4096 + p0 + q * 16;
    uint4 q0 = *(const uint4*)hp, q1 = *(const uint4*)(hp + 8);
    unsigned short e[16], r[16];
    *(uint4*)&e[0] = q0; *(uint4*)&e[8] = q1;
#pragma unroll
    for (int j = 0; j < 16; j++)
      r[j] = f2bf(fmaxf(fmaf(bf2f(e[j]), sc, sh), 0.f));
    *(uint4*)&T[cl][q * 16]     = *(uint4*)&r[0];
    *(uint4*)&T[cl][q * 16 + 8] = *(uint4*)&r[8];
  }
  __syncthreads();
  {
    int pl = t >> 2, qc = t & 3;
    unsigned short r[16];
#pragma unroll
    for (int j = 0; j < 16; j++) r[j] = T[qc * 16 + j][pl];
    unsigned short* op = h1T + (size_t)(b * 4096 + p0 + pl) * 128 + c0 + qc * 16;
    *(uint4*)op       = *(uint4*)&r[0];
    *(uint4*)(op + 8) = *(uint4*)&r[8];
  }
}

// ---------- K3 fallback: BN1 + ReLU in place on h1 ----------
__global__ void k_bn1(unsigned short* __restrict__ h1, const void* __restrict__ g1,
                      const void* __restrict__ be1) {
  const int f = g_isf32;
  int gid = blockIdx.x * 256 + threadIdx.x;
  size_t base = (size_t)gid * 8;
  int o = (int)((base >> 12) & 127);
  float mu = g_stats[o] * (1.f / 32768.f);
  float var = g_stats[128 + o] * (1.f / 32768.f) - mu * mu;
  float sc = rsqrtf(var + 1e-5f) * ldi(g1, o, f);
  float sh = ldi(be1, o, f) - mu * sc;
  uint4 p = *(const uint4*)(h1 + base);
  unsigned int pp[4] = {p.x, p.y, p.z, p.w};
  unsigned int r[4];
#pragma unroll
  for (int i = 0; i < 4; i++) {
    float f0 = fmaxf(fmaf(bf2f((unsigned short)(pp[i] & 0xffff)), sc, sh), 0.f);
    float f1 = fmaxf(fmaf(bf2f((unsigned short)(pp[i] >> 16)), sc, sh), 0.f);
    r[i] = pk2(f0, f1);
  }
  *(uint4*)(h1 + base) = make_uint4(r[0], r[1], r[2], r[3]);
}

// ---------- K4 (fast): parity-decomposed transposed conv as MFMA GEMM ----------
// grid (nt=32, par=4, b=8).  Reads channel-last h1T -> vectorized B staging.
__global__ __launch_bounds__(256) void k_ctgemm(
    const unsigned short* __restrict__ h1T,  // [b][4096 pos][128 ch]
    const unsigned short* __restrict__ Apar,
    void* __restrict__ out2) {
  const int f = g_isf32;
  const int nt = blockIdx.x, par = blockIdx.y, b = blockIdx.z;
  const int py = par >> 1, px = par & 1;
  const int t = threadIdx.x;
  const int wv = t >> 6, L = t & 63;
  const int quad = L >> 4, l15 = L & 15;
  const int wm = (wv >> 1) * 64, wn = (wv & 1) * 64;
  __shared__ unsigned short As[128][40];
  __shared__ unsigned short Bs[128][40];
  f32x4 acc[4][4] = {};
  const int y0 = nt * 2;
  const unsigned short* Ap = Apar + (size_t)par * 128 * 512;
  const unsigned short* hb = h1T + (size_t)b * 4096 * 128;
  const int sp = t >> 1, shalf = t & 1;   // pos 0..127, 16-ch half of 32-chunk
  const int srr = sp >> 6, sx = sp & 63;

  for (int kk = 0; kk < 512; kk += 32) {
    const int tap = kk >> 7, ic = kk & 127;
    const int a = tap >> 1, bb = tap & 1;
    const int ya = (py == 0) ? (a ? -1 : 0) : (a ? 0 : 1);
    const int xb = (px == 0) ? (bb ? -1 : 0) : (bb ? 0 : 1);
    __syncthreads();
    {   // A-tile 128x32
      int m = t >> 1, seg = t & 1;
      const unsigned short* ap = Ap + (size_t)m * 512 + kk + seg * 16;
      uint4 q0 = *(const uint4*)(ap);
      uint4 q1 = *(const uint4*)(ap + 8);
      *(uint4*)&As[m][seg * 16]     = q0;
      *(uint4*)&As[m][seg * 16 + 8] = q1;
    }
    {   // B-tile: 128 pos x 32 ch, vectorized from channel-last h1T, zero-padded
      int srcy = y0 + srr + ya;
      int srcx = sx + xb;
      uint4 q0 = make_uint4(0, 0, 0, 0), q1 = q0;
      if (srcy >= 0 && srcy < 64 && srcx >= 0 && srcx < 64) {
        const unsigned short* hp = hb + ((size_t)(srcy * 64 + srcx)) * 128 + ic + shalf * 16;
        q0 = *(const uint4*)(hp);
        q1 = *(const uint4*)(hp + 8);
      }
      *(uint4*)&Bs[sp][shalf * 16]     = q0;
      *(uint4*)&Bs[sp][shalf * 16 + 8] = q1;
    }
    __syncthreads();
    const int ar = quad * 8;
    bf16x8 af[4], bfr[4];
#pragma unroll
    for (int tm = 0; tm < 4; tm++) af[tm]  = *(const bf16x8*)&As[wm + tm * 16 + l15][ar];
#pragma unroll
    for (int tn = 0; tn < 4; tn++) bfr[tn] = *(const bf16x8*)&Bs[wn + tn * 16 + l15][ar];
#pragma unroll
    for (int tm = 0; tm < 4; tm++)
#pragma unroll
      for (int tn = 0; tn < 4; tn++)
        acc[tm][tn] = __builtin_amdgcn_mfma_f32_16x16x32_bf16(af[tm], bfr[tn], acc[tm][tn], 0, 0, 0);
  }

#pragma unroll
  for (int tm = 0; tm < 4; tm++) {
#pragma unroll
    for (int r = 0; r < 4; r++) {
      int m = wm + tm * 16 + quad * 4 + r;
      float s = 0.f, q = 0.f;
#pragma unroll
      for (int tn = 0; tn < 4; tn++) {
        float v = acc[tm][tn][r];
        int n = wn + tn * 16 + l15;
        int yy = 2 * (y0 + (n >> 6)) + py;
        int xx = 2 * (n & 63) + px;
        size_t ofs = (size_t)((b * 128 + m) * 128 + yy) * 128 + xx;
        if (f) ((float*)out2)[ofs] = v;
        else   ((unsigned short*)out2)[ofs] = f2bf(v);
        s += v; q += v * v;
      }
#pragma unroll
      for (int msk2 = 1; msk2 < 16; msk2 <<= 1) {
        s += __shfl_xor(s, msk2, 64);
        q += __shfl_xor(q, msk2, 64);
      }
      if (l15 == 0) { atomicAdd(&g_stats[256 + m], s); atomicAdd(&g_stats[384 + m], q); }
    }
  }
}

// ---------- K4 fallback: fp32 VALU transposed conv ----------
__global__ __launch_bounds__(256) void k_ctconv(
    const unsigned short* __restrict__ h1n, const float* __restrict__ wctT,
    void* __restrict__ out2) {
  const int f = g_isf32;
  const int y = blockIdx.x, b = blockIdx.y;
  const int t = threadIdx.x;
  const int og = t >> 3, xg = t & 7;
  __shared__ float hs[2 * 32 * 68];
  int kr0, kr1, r0, r1;
  if ((y & 1) == 0) { kr0 = 1; r0 = y >> 1; kr1 = 3; r1 = (y >> 1) - 1; }
  else              { kr0 = 0; r0 = (y + 1) >> 1; kr1 = 2; r1 = (y - 1) >> 1; }
  float acc[4][16];
#pragma unroll
  for (int j = 0; j < 4; j++)
#pragma unroll
    for (int i = 0; i < 16; i++) acc[j][i] = 0.f;

  for (int ihc = 0; ihc < 4; ihc++) {
    __syncthreads();
    for (int e = t; e < 2 * 32 * 64; e += 256) {
      int rr = e >> 11, rem = e & 2047, il = rem >> 6, w = rem & 63;
      int i = ihc * 32 + il;
      int row = rr ? r1 : r0;
      float v = 0.f;
      if (row >= 0 && row < 64)
        v = bf2f(h1n[(size_t)((b * 128 + i) * 64 + row) * 64 + w]);
      hs[(rr * 32 + il) * 68 + w + 1] = v;
    }
    for (int e = t; e < 64; e += 256) {
      int base = e * 68;
      hs[base] = 0.f; hs[base + 65] = 0.f; hs[base + 66] = 0.f; hs[base + 67] = 0.f;
    }
    __syncthreads();
    for (int il = 0; il < 32; il++) {
      const int i = ihc * 32 + il;
      float br[2][12];
#pragma unroll
      for (int rr = 0; rr < 2; rr++) {
        const float* p = &hs[(rr * 32 + il) * 68 + xg * 8];
        float4 q0 = *(const float4*)(p);
        float4 q1 = *(const float4*)(p + 4);
        float4 q2 = *(const float4*)(p + 8);
        br[rr][0] = q0.x; br[rr][1] = q0.y; br[rr][2] = q0.z; br[rr][3] = q0.w;
        br[rr][4] = q1.x; br[rr][5] = q1.y; br[rr][6] = q1.z; br[rr][7] = q1.w;
        br[rr][8] = q2.x; br[rr][9] = q2.y; br[rr][10] = q2.z; br[rr][11] = q2.w;
      }
      float a[2][4][4];
#pragma unroll
      for (int rr = 0; rr < 2; rr++) {
        const int krr = rr ? kr1 : kr0;
#pragma unroll
        for (int kc = 0; kc < 4; kc++) {
          float4 av = *(const float4*)&wctT[((size_t)(krr * 4 + kc) * 128 + i) * 128 + og * 4];
          a[rr][kc][0] = av.x; a[rr][kc][1] = av.y; a[rr][kc][2] = av.z; a[rr][kc][3] = av.w;
        }
      }
#pragma unroll
      for (int xi = 0; xi < 16; xi++) {
        const int u = xi >> 1;
        const int kcA = (xi & 1) ? 0 : 1;
        const int lwA = (xi & 1) ? u + 2 : u + 1;
        const int kcB = (xi & 1) ? 2 : 3;
        const int lwB = (xi & 1) ? u + 1 : u;
#pragma unroll
        for (int rr = 0; rr < 2; rr++) {
#pragma unroll
          for (int j = 0; j < 4; j++) {
            acc[j][xi] = fmaf(a[rr][kcA][j], br[rr][lwA], acc[j][xi]);
            acc[j][xi] = fmaf(a[rr][kcB][j], br[rr][lwB], acc[j][xi]);
          }
        }
      }
    }
  }
#pragma unroll
  for (int j = 0; j < 4; j++) {
    const int o = og * 4 + j;
    float s = 0.f, q = 0.f;
#pragma unroll
    for (int xi = 0; xi < 16; xi++) { s += acc[j][xi]; q += acc[j][xi] * acc[j][xi]; }
    size_t ofs = (size_t)((b * 128 + o) * 128 + y) * 128 + xg * 16;
    if (f) {
      float* op = (float*)out2 + ofs;
#pragma unroll
      for (int v4 = 0; v4 < 4; v4++)
        ((float4*)op)[v4] = make_float4(acc[j][4 * v4], acc[j][4 * v4 + 1],
                                        acc[j][4 * v4 + 2], acc[j][4 * v4 + 3]);
    } else {
      unsigned int w_[8];
#pragma unroll
      for (int xi = 0; xi < 8; xi++) w_[xi] = pk2(acc[j][2 * xi], acc[j][2 * xi + 1]);
      unsigned short* op = (unsigned short*)out2 + ofs;
      *(uint4*)(op)     = make_uint4(w_[0], w_[1], w_[2], w_[3]);
      *(uint4*)(op + 8) = make_uint4(w_[4], w_[5], w_[6], w_[7]);
    }
#pragma unroll
    for (int m = 1; m < 8; m <<= 1) {
      s += __shfl_xor(s, m, 64);
      q += __shfl_xor(q, m, 64);
    }
    if (xg == 0) { atomicAdd(&g_stats[256 + o], s); atomicAdd(&g_stats[384 + o], q); }
  }
}

// ---------- K5: BN2 + ReLU in place on d_out ----------
__global__ void k_bn2(void* __restrict__ out2, const void* __restrict__ g2,
                      const void* __restrict__ be2) {
  const int f = g_isf32;
  int gid = blockIdx.x * 256 + threadIdx.x;
  size_t base = (size_t)gid * 8;
  int o = (int)((base >> 14) & 127);
  float mu = g_stats[256 + o] * (1.f / 131072.f);
  float var = g_stats[384 + o] * (1.f / 131072.f) - mu * mu;
  float sc = rsqrtf(var + 1e-5f) * ldi(g2, o, f);
  float sh = ldi(be2, o, f) - mu * sc;
  if (f) {
    float4* op = (float4*)out2 + gid * 2;
    float4 p0 = op[0], p1 = op[1];
    p0.x = fmaxf(fmaf(p0.x, sc, sh), 0.f); p0.y = fmaxf(fmaf(p0.y, sc, sh), 0.f);
    p0.z = fmaxf(fmaf(p0.z, sc, sh), 0.f); p0.w = fmaxf(fmaf(p0.w, sc, sh), 0.f);
    p1.x = fmaxf(fmaf(p1.x, sc, sh), 0.f); p1.y = fmaxf(fmaf(p1.y, sc, sh), 0.f);
    p1.z = fmaxf(fmaf(p1.z, sc, sh), 0.f); p1.w = fmaxf(fmaf(p1.w, sc, sh), 0.f);
    op[0] = p0; op[1] = p1;
  } else {
    unsigned short* ob = (unsigned short*)out2 + base;
    uint4 p = *(const uint4*)ob;
    unsigned int pp[4] = {p.x, p.y, p.z, p.w};
    unsigned int r[4];
#pragma unroll
    for (int i = 0; i < 4; i++) {
      float f0 = fmaxf(fmaf(bf2f((unsigned short)(pp[i] & 0xffff)), sc, sh), 0.f);
      float f1 = fmaxf(fmaf(bf2f((unsigned short)(pp[i] >> 16)), sc, sh), 0.f);
      r[i] = pk2(f0, f1);
    }
    *(uint4*)ob = make_uint4(r[0], r[1], r[2], r[3]);
  }
}

// ---------- launch ----------
extern "C" void kernel_launch(void* const* d_in, const int* in_sizes, int n_in,
                              void* d_out, int out_size, void* d_ws, size_t ws_size,
                              hipStream_t stream) {
  const void* x     = d_in[0];
  const void* w_off = d_in[1];
  const void* b_off = d_in[2];
  const void* w_dcn = d_in[3];
  const void* b_dcn = d_in[4];
  const void* g1    = d_in[5];
  const void* be1   = d_in[6];
  const void* w_ct  = d_in[7];
  const void* g2    = d_in[8];
  const void* be2   = d_in[9];

  char* ws = (char*)d_ws;
  const bool fast = ws_size >= (size_t)166000000;

  unsigned short* Sbuf; unsigned short* h1; float* om; float* wdcnT; float* wctT;
  float* woffT; unsigned short* wdcnA; unsigned short* AparB; unsigned short* h1T;
  if (fast) {
    Sbuf  = (unsigned short*)(ws + 0);            // 150,994,944 B
    h1    = (unsigned short*)(ws + 150994944);    //   8,388,608 B
    om    = (float*)(ws + 159383552);             //   3,538,944 B
    wdcnT = (float*)(ws + 162922496);             //   1,179,648 B (dead in fast path)
    wctT  = (float*)(ws + 164102144);             //   1,048,576 B
    woffT = (float*)(ws + 165150720);             //     248,832 B
    wdcnA = (unsigned short*)(ws + 165399552);    //     589,824 B -> 165,989,376
    AparB = (unsigned short*)(ws + 162922496);    // 524,288 B, aliases wdcnT
    h1T   = (unsigned short*)(ws + 0);            // 8,388,608 B, aliases Sbuf (dead after k_gemm_dcn)
  } else {
    Sbuf  = nullptr;
    h1    = (unsigned short*)(ws + 0);
    om    = (float*)(ws + 8388608);
    wdcnT = (float*)(ws + 11927552);
    wctT  = (float*)(ws + 13107200);
    woffT = (float*)(ws + 14155776);
    wdcnA = (unsigned short*)(ws + 14404608);
    AparB = nullptr;
    h1T   = nullptr;
  }

  k_detect<<<dim3(1), 256, 0, stream>>>((const unsigned short*)x);
  k_prep<<<dim3(3571), 256, 0, stream>>>(w_dcn, w_ct, w_off, wdcnT, wctT, woffT, wdcnA);
  k_offconv<<<dim3(64, 8), 256, 0, stream>>>(x, b_off, woffT, om);
  if (fast) {
    k_prep2<<<dim3(1024), 256, 0, stream>>>(wctT, AparB);
    k_sample<<<dim3(64, 8, 4), 256, 0, stream>>>(x, om, Sbuf);
    k_gemm_dcn<<<dim3(32, 8), 256, 0, stream>>>(wdcnA, Sbuf, b_dcn, h1);
    k_bn1t<<<dim3(64, 2, 8), 256, 0, stream>>>(h1, g1, be1, h1T);
    k_ctgemm<<<dim3(32, 4, 8), 256, 0, stream>>>(h1T, AparB, d_out);
  } else {
    k_dcn<<<dim3(64, 8), 256, 0, stream>>>(x, om, wdcnT, b_dcn, h1);
    k_bn1<<<dim3(2048), 256, 0, stream>>>(h1, g1, be1);
    k_ctconv<<<dim3(128, 8), 256, 0, stream>>>(h1, wctT, d_out);
  }
  k_bn2<<<dim3(8192), 256, 0, stream>>>(d_out, g2, be2);
}